// Round 1
// baseline (1191.713 us; speedup 1.0000x reference)
//
#include <hip/hip_runtime.h>
#include <hip/hip_bf16.h>
#include <cstdint>
#include <cstddef>

using bf16 = __hip_bfloat16;

constexpr int Bc = 8;
constexpr int Tc = 4097;
constexpr int Dc = 512;     // model dim
constexpr int Hc = 8;
constexpr int HDc = 64;     // head dim
constexpr int Mrows = Bc * Tc;  // 32776

__device__ __forceinline__ float bf2f(unsigned short u) {
    union { unsigned int i; float f; } v;
    v.i = ((unsigned int)u) << 16;
    return v.f;
}

// ---------------------------------------------------------------------------
// Kernel 1: qkv = x @ w_qkv   (fp32 x fp32 -> bf16)
// M=32776, N=1536, K=512. Tiles: BM=BN=64, BK=32. 256 threads, 4x4 micro.
// ---------------------------------------------------------------------------
__global__ __launch_bounds__(256)
void k_gemm_qkv(const float* __restrict__ A, const float* __restrict__ W,
                bf16* __restrict__ C, int M, int N, int K)
{
    __shared__ float As[32][64];  // [k][m]
    __shared__ float Bs[32][64];  // [k][n]

    const int tid = threadIdx.x;
    const int bm = blockIdx.x * 64;
    const int bn = blockIdx.y * 64;
    const int tx = tid & 15, ty = tid >> 4;

    float acc[4][4] = {};

    for (int k0 = 0; k0 < K; k0 += 32) {
        // load A tile (64 rows x 32 k), float4 along k
        #pragma unroll
        for (int it = 0; it < 2; ++it) {
            int f = tid + it * 256;
            int row = f >> 3;
            int kq = (f & 7) * 4;
            float4 v = make_float4(0.f, 0.f, 0.f, 0.f);
            if (bm + row < M)
                v = *(const float4*)(A + (size_t)(bm + row) * K + k0 + kq);
            As[kq + 0][row] = v.x;
            As[kq + 1][row] = v.y;
            As[kq + 2][row] = v.z;
            As[kq + 3][row] = v.w;
        }
        // load B tile (32 k x 64 n), float4 along n
        #pragma unroll
        for (int it = 0; it < 2; ++it) {
            int f = tid + it * 256;
            int kr = f >> 4;
            int nq = (f & 15) * 4;
            *(float4*)&Bs[kr][nq] =
                *(const float4*)(W + (size_t)(k0 + kr) * N + bn + nq);
        }
        __syncthreads();

        #pragma unroll
        for (int kk = 0; kk < 32; ++kk) {
            float4 a = *(const float4*)&As[kk][ty * 4];
            float4 b = *(const float4*)&Bs[kk][tx * 4];
            float av[4] = {a.x, a.y, a.z, a.w};
            float bv[4] = {b.x, b.y, b.z, b.w};
            #pragma unroll
            for (int i = 0; i < 4; ++i)
                #pragma unroll
                for (int j = 0; j < 4; ++j)
                    acc[i][j] = fmaf(av[i], bv[j], acc[i][j]);
        }
        __syncthreads();
    }

    #pragma unroll
    for (int i = 0; i < 4; ++i) {
        int r = bm + ty * 4 + i;
        if (r < M) {
            bf16* cp = C + (size_t)r * N + bn + tx * 4;
            #pragma unroll
            for (int j = 0; j < 4; ++j) cp[j] = __float2bfloat16(acc[i][j]);
        }
    }
}

// ---------------------------------------------------------------------------
// Kernel 2: window attention for tokens 1..4096.
// One block per (window n, head h, batch b). 256 threads.
// ---------------------------------------------------------------------------
__global__ __launch_bounds__(256)
void k_attn_win(const bf16* __restrict__ qkv, bf16* __restrict__ aout)
{
    constexpr int SW = 68;              // padded stride (floats)
    __shared__ float smem[4 * 64 * SW]; // 69.6 KB
    float* qT = smem;                   // [d][i]   (later reused as pT [j][i])
    float* kT = smem + 64 * SW;         // [d][j]
    float* vS = smem + 2 * 64 * SW;     // [j][d]
    float* sS = smem + 3 * 64 * SW;     // [i][j]
    float* pT = qT;

    const int n = blockIdx.x, h = blockIdx.y, b = blockIdx.z;
    const int tid = threadIdx.x;
    const bf16* base = qkv + ((size_t)b * Tc + 1 + (size_t)n * 64) * 1536 + h * 64;

    // Load q,k,v 64x64 tiles
    #pragma unroll
    for (int it = 0; it < 4; ++it) {
        int u = tid + it * 256;
        int row = u >> 4;
        int c4 = (u & 15) * 4;
        size_t roff = (size_t)row * 1536 + c4;
        ushort4 uq = *(const ushort4*)(base + roff);
        ushort4 uk = *(const ushort4*)(base + roff + 512);
        ushort4 uv = *(const ushort4*)(base + roff + 1024);
        qT[(c4 + 0) * SW + row] = bf2f(uq.x);
        qT[(c4 + 1) * SW + row] = bf2f(uq.y);
        qT[(c4 + 2) * SW + row] = bf2f(uq.z);
        qT[(c4 + 3) * SW + row] = bf2f(uq.w);
        kT[(c4 + 0) * SW + row] = bf2f(uk.x);
        kT[(c4 + 1) * SW + row] = bf2f(uk.y);
        kT[(c4 + 2) * SW + row] = bf2f(uk.z);
        kT[(c4 + 3) * SW + row] = bf2f(uk.w);
        float4 vv = make_float4(bf2f(uv.x), bf2f(uv.y), bf2f(uv.z), bf2f(uv.w));
        *(float4*)&vS[row * SW + c4] = vv;
    }
    __syncthreads();

    const int tx = tid & 15, ty = tid >> 4;

    // S = q @ k^T * scale
    float acc[4][4] = {};
    #pragma unroll
    for (int dd = 0; dd < 64; ++dd) {
        float4 a = *(const float4*)&qT[dd * SW + ty * 4];
        float4 bb = *(const float4*)&kT[dd * SW + tx * 4];
        float av[4] = {a.x, a.y, a.z, a.w};
        float bv[4] = {bb.x, bb.y, bb.z, bb.w};
        #pragma unroll
        for (int i = 0; i < 4; ++i)
            #pragma unroll
            for (int j = 0; j < 4; ++j)
                acc[i][j] = fmaf(av[i], bv[j], acc[i][j]);
    }
    #pragma unroll
    for (int i = 0; i < 4; ++i)
        #pragma unroll
        for (int j = 0; j < 4; ++j)
            sS[(ty * 4 + i) * SW + tx * 4 + j] = acc[i][j] * 0.125f;
    __syncthreads();

    // row softmax (one thread per row), write transposed into pT[j][i]
    if (tid < 64) {
        int r = tid;
        float m = -1e30f;
        for (int j = 0; j < 64; ++j) m = fmaxf(m, sS[r * SW + j]);
        float s = 0.f;
        for (int j = 0; j < 64; ++j) {
            float e = __expf(sS[r * SW + j] - m);
            sS[r * SW + j] = e;
            s += e;
        }
        float inv = 1.f / s;
        for (int j = 0; j < 64; ++j) pT[j * SW + r] = sS[r * SW + j] * inv;
    }
    __syncthreads();

    // O = P @ V
    float o[4][4] = {};
    #pragma unroll
    for (int j = 0; j < 64; ++j) {
        float4 p = *(const float4*)&pT[j * SW + ty * 4];
        float4 v = *(const float4*)&vS[j * SW + tx * 4];
        float pv[4] = {p.x, p.y, p.z, p.w};
        float vv[4] = {v.x, v.y, v.z, v.w};
        #pragma unroll
        for (int i = 0; i < 4; ++i)
            #pragma unroll
            for (int jj = 0; jj < 4; ++jj)
                o[i][jj] = fmaf(pv[i], vv[jj], o[i][jj]);
    }

    #pragma unroll
    for (int i = 0; i < 4; ++i) {
        int t = 1 + n * 64 + ty * 4 + i;
        bf16* op = aout + ((size_t)b * Tc + t) * Dc + h * 64 + tx * 4;
        #pragma unroll
        for (int jj = 0; jj < 4; ++jj) op[jj] = __float2bfloat16(o[i][jj]);
    }
}

// ---------------------------------------------------------------------------
// Kernel 3: token-0 full attention over all T keys. One wave per (b,h).
// ---------------------------------------------------------------------------
__global__ __launch_bounds__(64)
void k_attn_tok0(const bf16* __restrict__ qkv, bf16* __restrict__ aout)
{
    const int h = blockIdx.x, b = blockIdx.y;
    const int lane = threadIdx.x;

    __shared__ float q0s[64];
    __shared__ float accs[64][65];

    q0s[lane] = bf2f(*(const unsigned short*)
        (qkv + (size_t)b * Tc * 1536 + h * 64 + lane));
    __syncthreads();

    float m = -1e30f, s = 0.f;
    float acc[64];
    #pragma unroll
    for (int d = 0; d < 64; ++d) acc[d] = 0.f;

    for (int t = lane; t < Tc; t += 64) {
        const bf16* kp = qkv + ((size_t)b * Tc + t) * 1536 + 512 + h * 64;
        float logit = 0.f;
        #pragma unroll
        for (int d4 = 0; d4 < 16; ++d4) {
            ushort4 ku = ((const ushort4*)kp)[d4];
            logit = fmaf(q0s[d4 * 4 + 0], bf2f(ku.x), logit);
            logit = fmaf(q0s[d4 * 4 + 1], bf2f(ku.y), logit);
            logit = fmaf(q0s[d4 * 4 + 2], bf2f(ku.z), logit);
            logit = fmaf(q0s[d4 * 4 + 3], bf2f(ku.w), logit);
        }
        logit *= 0.125f;
        float nm = fmaxf(m, logit);
        float corr = __expf(m - nm);
        float p = __expf(logit - nm);
        s = s * corr + p;
        const bf16* vp = kp + 512;
        #pragma unroll
        for (int d4 = 0; d4 < 16; ++d4) {
            ushort4 vu = ((const ushort4*)vp)[d4];
            acc[d4 * 4 + 0] = fmaf(acc[d4 * 4 + 0], corr, p * bf2f(vu.x));
            acc[d4 * 4 + 1] = fmaf(acc[d4 * 4 + 1], corr, p * bf2f(vu.y));
            acc[d4 * 4 + 2] = fmaf(acc[d4 * 4 + 2], corr, p * bf2f(vu.z));
            acc[d4 * 4 + 3] = fmaf(acc[d4 * 4 + 3], corr, p * bf2f(vu.w));
        }
        m = nm;
    }

    // cross-lane combine
    float M = m;
    #pragma unroll
    for (int off = 1; off < 64; off <<= 1) M = fmaxf(M, __shfl_xor(M, off));
    float c = __expf(m - M);
    s *= c;
    #pragma unroll
    for (int d = 0; d < 64; ++d) acc[d] *= c;
    float S = s;
    #pragma unroll
    for (int off = 1; off < 64; off <<= 1) S += __shfl_xor(S, off);

    #pragma unroll
    for (int d = 0; d < 64; ++d) accs[lane][d] = acc[d];
    __syncthreads();

    float o = 0.f;
    #pragma unroll
    for (int i = 0; i < 64; ++i) o += accs[i][lane];

    aout[(size_t)b * Tc * Dc + h * 64 + lane] = __float2bfloat16(o / S);
}

// ---------------------------------------------------------------------------
// Kernel 4: out = attn_out @ w_out   (bf16 x fp32 -> fp32)
// M=32776, N=512, K=512.
// ---------------------------------------------------------------------------
__global__ __launch_bounds__(256)
void k_gemm_out(const bf16* __restrict__ A, const float* __restrict__ W,
                float* __restrict__ C, int M, int N, int K)
{
    __shared__ float As[32][64];
    __shared__ float Bs[32][64];

    const int tid = threadIdx.x;
    const int bm = blockIdx.x * 64;
    const int bn = blockIdx.y * 64;
    const int tx = tid & 15, ty = tid >> 4;

    float acc[4][4] = {};

    for (int k0 = 0; k0 < K; k0 += 32) {
        #pragma unroll
        for (int it = 0; it < 2; ++it) {
            int f = tid + it * 256;
            int row = f >> 3;
            int kq = (f & 7) * 4;
            float4 v = make_float4(0.f, 0.f, 0.f, 0.f);
            if (bm + row < M) {
                ushort4 u = *(const ushort4*)(A + (size_t)(bm + row) * K + k0 + kq);
                v = make_float4(bf2f(u.x), bf2f(u.y), bf2f(u.z), bf2f(u.w));
            }
            As[kq + 0][row] = v.x;
            As[kq + 1][row] = v.y;
            As[kq + 2][row] = v.z;
            As[kq + 3][row] = v.w;
        }
        #pragma unroll
        for (int it = 0; it < 2; ++it) {
            int f = tid + it * 256;
            int kr = f >> 4;
            int nq = (f & 15) * 4;
            *(float4*)&Bs[kr][nq] =
                *(const float4*)(W + (size_t)(k0 + kr) * N + bn + nq);
        }
        __syncthreads();

        #pragma unroll
        for (int kk = 0; kk < 32; ++kk) {
            float4 a = *(const float4*)&As[kk][ty * 4];
            float4 b = *(const float4*)&Bs[kk][tx * 4];
            float av[4] = {a.x, a.y, a.z, a.w};
            float bv[4] = {b.x, b.y, b.z, b.w};
            #pragma unroll
            for (int i = 0; i < 4; ++i)
                #pragma unroll
                for (int j = 0; j < 4; ++j)
                    acc[i][j] = fmaf(av[i], bv[j], acc[i][j]);
        }
        __syncthreads();
    }

    #pragma unroll
    for (int i = 0; i < 4; ++i) {
        int r = bm + ty * 4 + i;
        if (r < M) {
            float4 v = make_float4(acc[i][0], acc[i][1], acc[i][2], acc[i][3]);
            *(float4*)(C + (size_t)r * N + bn + tx * 4) = v;
        }
    }
}

// ---------------------------------------------------------------------------
extern "C" void kernel_launch(void* const* d_in, const int* in_sizes, int n_in,
                              void* d_out, int out_size, void* d_ws, size_t ws_size,
                              hipStream_t stream)
{
    const float* x     = (const float*)d_in[0];
    const float* w_qkv = (const float*)d_in[1];
    const float* w_out = (const float*)d_in[2];
    float* out = (float*)d_out;

    const size_t qkv_elems = (size_t)Mrows * 1536;  // 50,343,936
    bf16* qkv  = (bf16*)d_ws;
    bf16* aout = (bf16*)((char*)d_ws + qkv_elems * sizeof(bf16));

    dim3 blk(256);

    // 1) qkv = x @ w_qkv
    k_gemm_qkv<<<dim3((Mrows + 63) / 64, 1536 / 64), blk, 0, stream>>>(
        x, w_qkv, qkv, Mrows, 1536, 512);

    // 2) window attention (tokens 1..4096)
    k_attn_win<<<dim3(64, Hc, Bc), blk, 0, stream>>>(qkv, aout);

    // 3) token-0 full attention
    k_attn_tok0<<<dim3(Hc, Bc), dim3(64), 0, stream>>>(qkv, aout);

    // 4) out = attn_out @ w_out
    k_gemm_out<<<dim3((Mrows + 63) / 64, 512 / 64), blk, 0, stream>>>(
        aout, w_out, out, Mrows, 512, 512);
}

// Round 2
// 396.796 us; speedup vs baseline: 3.0033x; 3.0033x over previous
//
#include <hip/hip_runtime.h>
#include <hip/hip_bf16.h>
#include <cstdint>
#include <cstddef>

using bf16 = __hip_bfloat16;
using short8 = __attribute__((ext_vector_type(8))) short;
using f32x4  = __attribute__((ext_vector_type(4))) float;

constexpr int Bc = 8;
constexpr int Tc = 4097;
constexpr int Dc = 512;         // model dim
constexpr int Hc = 8;
constexpr int Mrows = Bc * Tc;  // 32776
constexpr int Mpad  = 32896;    // 257 * 128

__device__ __forceinline__ float bf2f(unsigned short u) {
    union { unsigned int i; float f; } v;
    v.i = ((unsigned int)u) << 16;
    return v.f;
}

__device__ __forceinline__ unsigned short f2b(float f) {
    union { float f; unsigned int i; } u; u.f = f;
    unsigned int r = u.i + 0x7FFFu + ((u.i >> 16) & 1u);  // RNE
    return (unsigned short)(r >> 16);
}

__device__ __forceinline__ void gload_lds16(const void* g, void* l) {
    __builtin_amdgcn_global_load_lds(
        (const __attribute__((address_space(1))) void*)g,
        (__attribute__((address_space(3))) void*)l, 16, 0, 0);
}

// ---------------------------------------------------------------------------
// Convert x (fp32 [Mrows][512]) -> bf16 [Mpad][512]; pad rows zeroed.
// ---------------------------------------------------------------------------
__global__ __launch_bounds__(256)
void k_cvt_x(const float* __restrict__ x, bf16* __restrict__ xb)
{
    size_t i8 = ((size_t)blockIdx.x * 256 + threadIdx.x) * 8;
    if (i8 >= (size_t)Mpad * 512) return;
    union { short s[8]; short8 v; } o;
    if (i8 < (size_t)Mrows * 512) {
        float4 v0 = *(const float4*)(x + i8);
        float4 v1 = *(const float4*)(x + i8 + 4);
        o.s[0] = (short)f2b(v0.x); o.s[1] = (short)f2b(v0.y);
        o.s[2] = (short)f2b(v0.z); o.s[3] = (short)f2b(v0.w);
        o.s[4] = (short)f2b(v1.x); o.s[5] = (short)f2b(v1.y);
        o.s[6] = (short)f2b(v1.z); o.s[7] = (short)f2b(v1.w);
    } else {
        o.v = short8{0,0,0,0,0,0,0,0};
    }
    *(short8*)((short*)xb + i8) = o.v;
}

// ---------------------------------------------------------------------------
// Convert + transpose weight: w fp32 [K][N] -> wT bf16 [N][K].
// ---------------------------------------------------------------------------
__global__ __launch_bounds__(256)
void k_cvt_wT(const float* __restrict__ w, bf16* __restrict__ wT, int K, int N)
{
    __shared__ float t[32][33];
    int bn = blockIdx.x * 32, bk = blockIdx.y * 32;
    int tx = threadIdx.x & 31, ty = threadIdx.x >> 5;  // 32 x 8
    #pragma unroll
    for (int j = 0; j < 4; ++j)
        t[ty + j * 8][tx] = w[(size_t)(bk + ty + j * 8) * N + bn + tx];
    __syncthreads();
    #pragma unroll
    for (int j = 0; j < 4; ++j)
        wT[(size_t)(bn + ty + j * 8) * K + bk + tx] =
            __float2bfloat16(t[tx][ty + j * 8]);
}

// ---------------------------------------------------------------------------
// MFMA bf16 GEMM (m97 structure): C[M][N] = A[Mpad][512] @ Bt[N][512]^T
// 128x128 tile, BK=32, 256 threads (4 waves, 2x2), 4x4 16x16x32 frags/wave.
// ---------------------------------------------------------------------------
template <typename OutT>
__global__ __launch_bounds__(256)
void k_gemm_mfma(const bf16* __restrict__ A, const bf16* __restrict__ Bt,
                 OutT* __restrict__ C, int N, int Mlim)
{
    __shared__ short lds[8192];           // As [0..4095], Bs [4096..8191]
    short* As = lds;
    short* Bs = lds + 4096;

    const int tid = threadIdx.x;
    const int wave = tid >> 6, lane = tid & 63;
    const int bm = blockIdx.x * 128, bn = blockIdx.y * 128;

    // staging addresses: flat 16B-unit index within 8KB tile
    const int flat0 = wave * 128 + lane;
    const int flat1 = flat0 + 64;
    const int rA0 = flat0 >> 2, pA0 = (flat0 & 3) * 8;
    const int rA1 = flat1 >> 2, pA1 = (flat1 & 3) * 8;

    const bf16* gA0 = A + (size_t)(bm + rA0) * 512 + pA0;
    const bf16* gA1 = A + (size_t)(bm + rA1) * 512 + pA1;
    const bf16* gB0 = Bt + (size_t)(bn + rA0) * 512 + pA0;
    const bf16* gB1 = Bt + (size_t)(bn + rA1) * 512 + pA1;
    short* lA0 = As + (wave * 2 + 0) * 512;  // 512 shorts = 1KB per wave-inst
    short* lA1 = As + (wave * 2 + 1) * 512;
    short* lB0 = Bs + (wave * 2 + 0) * 512;
    short* lB1 = Bs + (wave * 2 + 1) * 512;

    const int m_base = (wave >> 1) * 64, n_base = (wave & 1) * 64;
    int aoff[4], boff[4];
    #pragma unroll
    for (int i = 0; i < 4; ++i) {
        aoff[i] = (m_base + i * 16 + (lane & 15)) * 32 + (lane >> 4) * 8;
        boff[i] = (n_base + i * 16 + (lane & 15)) * 32 + (lane >> 4) * 8;
    }

    f32x4 acc[4][4] = {};

    for (int k0 = 0; k0 < 512; k0 += 32) {
        gload_lds16(gA0, lA0);
        gload_lds16(gA1, lA1);
        gload_lds16(gB0, lB0);
        gload_lds16(gB1, lB1);
        gA0 += 32; gA1 += 32; gB0 += 32; gB1 += 32;
        __syncthreads();

        short8 a[4], b[4];
        #pragma unroll
        for (int i = 0; i < 4; ++i) a[i] = *(const short8*)(As + aoff[i]);
        #pragma unroll
        for (int i = 0; i < 4; ++i) b[i] = *(const short8*)(Bs + boff[i]);
        #pragma unroll
        for (int mi = 0; mi < 4; ++mi)
            #pragma unroll
            for (int ni = 0; ni < 4; ++ni)
                acc[mi][ni] = __builtin_amdgcn_mfma_f32_16x16x32_bf16(
                    a[mi], b[ni], acc[mi][ni], 0, 0, 0);
        __syncthreads();
    }

    // epilogue: D row=(lane>>4)*4+r, col=lane&15 within each 16x16 frag
    #pragma unroll
    for (int mi = 0; mi < 4; ++mi) {
        #pragma unroll
        for (int ni = 0; ni < 4; ++ni) {
            int gr = bm + m_base + mi * 16 + (lane >> 4) * 4;
            int gc = bn + n_base + ni * 16 + (lane & 15);
            #pragma unroll
            for (int r = 0; r < 4; ++r) {
                if (gr + r < Mlim) {
                    float v = acc[mi][ni][r];
                    if constexpr (sizeof(OutT) == 2)
                        C[(size_t)(gr + r) * N + gc] = __float2bfloat16(v);
                    else
                        C[(size_t)(gr + r) * N + gc] = v;
                }
            }
        }
    }
}

// ---------------------------------------------------------------------------
// Window attention for tokens 1..4096. One block per (window, head, batch).
// ---------------------------------------------------------------------------
__global__ __launch_bounds__(256)
void k_attn_win(const bf16* __restrict__ qkv, bf16* __restrict__ aout)
{
    constexpr int SW = 68;
    __shared__ float smem[4 * 64 * SW];
    float* qT = smem;
    float* kT = smem + 64 * SW;
    float* vS = smem + 2 * 64 * SW;
    float* sS = smem + 3 * 64 * SW;
    float* pT = qT;

    const int n = blockIdx.x, h = blockIdx.y, b = blockIdx.z;
    const int tid = threadIdx.x;
    const bf16* base = qkv + ((size_t)b * Tc + 1 + (size_t)n * 64) * 1536 + h * 64;

    #pragma unroll
    for (int it = 0; it < 4; ++it) {
        int u = tid + it * 256;
        int row = u >> 4;
        int c4 = (u & 15) * 4;
        size_t roff = (size_t)row * 1536 + c4;
        ushort4 uq = *(const ushort4*)(base + roff);
        ushort4 uk = *(const ushort4*)(base + roff + 512);
        ushort4 uv = *(const ushort4*)(base + roff + 1024);
        qT[(c4 + 0) * SW + row] = bf2f(uq.x);
        qT[(c4 + 1) * SW + row] = bf2f(uq.y);
        qT[(c4 + 2) * SW + row] = bf2f(uq.z);
        qT[(c4 + 3) * SW + row] = bf2f(uq.w);
        kT[(c4 + 0) * SW + row] = bf2f(uk.x);
        kT[(c4 + 1) * SW + row] = bf2f(uk.y);
        kT[(c4 + 2) * SW + row] = bf2f(uk.z);
        kT[(c4 + 3) * SW + row] = bf2f(uk.w);
        float4 vv = make_float4(bf2f(uv.x), bf2f(uv.y), bf2f(uv.z), bf2f(uv.w));
        *(float4*)&vS[row * SW + c4] = vv;
    }
    __syncthreads();

    const int tx = tid & 15, ty = tid >> 4;

    float acc[4][4] = {};
    #pragma unroll
    for (int dd = 0; dd < 64; ++dd) {
        float4 a = *(const float4*)&qT[dd * SW + ty * 4];
        float4 bb = *(const float4*)&kT[dd * SW + tx * 4];
        float av[4] = {a.x, a.y, a.z, a.w};
        float bv[4] = {bb.x, bb.y, bb.z, bb.w};
        #pragma unroll
        for (int i = 0; i < 4; ++i)
            #pragma unroll
            for (int j = 0; j < 4; ++j)
                acc[i][j] = fmaf(av[i], bv[j], acc[i][j]);
    }
    #pragma unroll
    for (int i = 0; i < 4; ++i)
        #pragma unroll
        for (int j = 0; j < 4; ++j)
            sS[(ty * 4 + i) * SW + tx * 4 + j] = acc[i][j] * 0.125f;
    __syncthreads();

    if (tid < 64) {
        int r = tid;
        float m = -1e30f;
        for (int j = 0; j < 64; ++j) m = fmaxf(m, sS[r * SW + j]);
        float s = 0.f;
        for (int j = 0; j < 64; ++j) {
            float e = __expf(sS[r * SW + j] - m);
            sS[r * SW + j] = e;
            s += e;
        }
        float inv = 1.f / s;
        for (int j = 0; j < 64; ++j) pT[j * SW + r] = sS[r * SW + j] * inv;
    }
    __syncthreads();

    float o[4][4] = {};
    #pragma unroll
    for (int j = 0; j < 64; ++j) {
        float4 p = *(const float4*)&pT[j * SW + ty * 4];
        float4 v = *(const float4*)&vS[j * SW + tx * 4];
        float pv[4] = {p.x, p.y, p.z, p.w};
        float vv[4] = {v.x, v.y, v.z, v.w};
        #pragma unroll
        for (int i = 0; i < 4; ++i)
            #pragma unroll
            for (int jj = 0; jj < 4; ++jj)
                o[i][jj] = fmaf(pv[i], vv[jj], o[i][jj]);
    }

    #pragma unroll
    for (int i = 0; i < 4; ++i) {
        int t = 1 + n * 64 + ty * 4 + i;
        bf16* op = aout + ((size_t)b * Tc + t) * Dc + h * 64 + tx * 4;
        #pragma unroll
        for (int jj = 0; jj < 4; ++jj) op[jj] = __float2bfloat16(o[i][jj]);
    }
}

// ---------------------------------------------------------------------------
// Token-0 full attention over all T keys. One wave per (b,h).
// ---------------------------------------------------------------------------
__global__ __launch_bounds__(64)
void k_attn_tok0(const bf16* __restrict__ qkv, bf16* __restrict__ aout)
{
    const int h = blockIdx.x, b = blockIdx.y;
    const int lane = threadIdx.x;

    __shared__ float q0s[64];
    __shared__ float accs[64][65];

    q0s[lane] = bf2f(*(const unsigned short*)
        (qkv + (size_t)b * Tc * 1536 + h * 64 + lane));
    __syncthreads();

    float m = -1e30f, s = 0.f;
    float acc[64];
    #pragma unroll
    for (int d = 0; d < 64; ++d) acc[d] = 0.f;

    for (int t = lane; t < Tc; t += 64) {
        const bf16* kp = qkv + ((size_t)b * Tc + t) * 1536 + 512 + h * 64;
        float logit = 0.f;
        #pragma unroll
        for (int d4 = 0; d4 < 16; ++d4) {
            ushort4 ku = ((const ushort4*)kp)[d4];
            logit = fmaf(q0s[d4 * 4 + 0], bf2f(ku.x), logit);
            logit = fmaf(q0s[d4 * 4 + 1], bf2f(ku.y), logit);
            logit = fmaf(q0s[d4 * 4 + 2], bf2f(ku.z), logit);
            logit = fmaf(q0s[d4 * 4 + 3], bf2f(ku.w), logit);
        }
        logit *= 0.125f;
        float nm = fmaxf(m, logit);
        float corr = __expf(m - nm);
        float p = __expf(logit - nm);
        s = s * corr + p;
        const bf16* vp = kp + 512;
        #pragma unroll
        for (int d4 = 0; d4 < 16; ++d4) {
            ushort4 vu = ((const ushort4*)vp)[d4];
            acc[d4 * 4 + 0] = fmaf(acc[d4 * 4 + 0], corr, p * bf2f(vu.x));
            acc[d4 * 4 + 1] = fmaf(acc[d4 * 4 + 1], corr, p * bf2f(vu.y));
            acc[d4 * 4 + 2] = fmaf(acc[d4 * 4 + 2], corr, p * bf2f(vu.z));
            acc[d4 * 4 + 3] = fmaf(acc[d4 * 4 + 3], corr, p * bf2f(vu.w));
        }
        m = nm;
    }

    float M = m;
    #pragma unroll
    for (int off = 1; off < 64; off <<= 1) M = fmaxf(M, __shfl_xor(M, off));
    float c = __expf(m - M);
    s *= c;
    #pragma unroll
    for (int d = 0; d < 64; ++d) acc[d] *= c;
    float S = s;
    #pragma unroll
    for (int off = 1; off < 64; off <<= 1) S += __shfl_xor(S, off);

    #pragma unroll
    for (int d = 0; d < 64; ++d) accs[lane][d] = acc[d];
    __syncthreads();

    float o = 0.f;
    #pragma unroll
    for (int i = 0; i < 64; ++i) o += accs[i][lane];

    aout[(size_t)b * Tc * Dc + h * 64 + lane] = __float2bfloat16(o / S);
}

// ---------------------------------------------------------------------------
extern "C" void kernel_launch(void* const* d_in, const int* in_sizes, int n_in,
                              void* d_out, int out_size, void* d_ws, size_t ws_size,
                              hipStream_t stream)
{
    const float* x     = (const float*)d_in[0];
    const float* w_qkv = (const float*)d_in[1];
    const float* w_out = (const float*)d_in[2];
    float* out = (float*)d_out;

    // ws layout (bf16 elems): qkv [Mpad*1536] | xa (xb & aout share) [Mpad*512]
    //                         | wqT [1536*512] | woT [512*512]   => ~136.8 MB
    bf16* qkv = (bf16*)d_ws;
    bf16* xa  = qkv + (size_t)Mpad * 1536;
    bf16* wqT = xa  + (size_t)Mpad * 512;
    bf16* woT = wqT + (size_t)1536 * 512;

    // 1) conversions
    {
        int nblk = (int)(((size_t)Mpad * 512 / 8 + 255) / 256);
        k_cvt_x<<<nblk, 256, 0, stream>>>(x, xa);
    }
    k_cvt_wT<<<dim3(48, 16), 256, 0, stream>>>(w_qkv, wqT, 512, 1536);
    k_cvt_wT<<<dim3(16, 16), 256, 0, stream>>>(w_out, woT, 512, 512);

    // 2) qkv = x @ w_qkv  (MFMA)
    k_gemm_mfma<bf16><<<dim3(257, 12), 256, 0, stream>>>(xa, wqT, qkv, 1536, Mpad);

    // 3) attention (window + token 0); writes aout (= xa buffer, now dead as xb)
    k_attn_win<<<dim3(64, Hc, Bc), 256, 0, stream>>>(qkv, xa);
    k_attn_tok0<<<dim3(Hc, Bc), dim3(64), 0, stream>>>(qkv, xa);

    // 4) out = attn_out @ w_out  (MFMA, fp32 out)
    k_gemm_mfma<float><<<dim3(257, 4), 256, 0, stream>>>(xa, woT, out, 512, Mrows);
}

// Round 3
// 283.836 us; speedup vs baseline: 4.1986x; 1.3980x over previous
//
#include <hip/hip_runtime.h>
#include <hip/hip_bf16.h>
#include <cstdint>
#include <cstddef>

using bf16 = __hip_bfloat16;
using short8 = __attribute__((ext_vector_type(8))) short;
using f32x4  = __attribute__((ext_vector_type(4))) float;

constexpr int Bc = 8;
constexpr int Tc = 4097;
constexpr int Dc = 512;         // model dim
constexpr int Hc = 8;
constexpr int Mrows = Bc * Tc;  // 32776
constexpr int Mpad  = 32896;    // 257 * 128
constexpr int NCh = 65;         // token-0 key chunks (64 keys each)

__device__ __forceinline__ float bf2f(unsigned short u) {
    union { unsigned int i; float f; } v;
    v.i = ((unsigned int)u) << 16;
    return v.f;
}

__device__ __forceinline__ unsigned short f2b(float f) {
    union { float f; unsigned int i; } u; u.f = f;
    unsigned int r = u.i + 0x7FFFu + ((u.i >> 16) & 1u);  // RNE
    return (unsigned short)(r >> 16);
}

__device__ __forceinline__ void gload_lds16(const void* g, void* l) {
    __builtin_amdgcn_global_load_lds(
        (const __attribute__((address_space(1))) void*)g,
        (__attribute__((address_space(3))) void*)l, 16, 0, 0);
}

// ---------------------------------------------------------------------------
// Convert x (fp32 [Mrows][512]) -> bf16 [Mpad][512]; pad rows zeroed.
// ---------------------------------------------------------------------------
__global__ __launch_bounds__(256)
void k_cvt_x(const float* __restrict__ x, bf16* __restrict__ xb)
{
    size_t i8 = ((size_t)blockIdx.x * 256 + threadIdx.x) * 8;
    if (i8 >= (size_t)Mpad * 512) return;
    union { short s[8]; short8 v; } o;
    if (i8 < (size_t)Mrows * 512) {
        float4 v0 = *(const float4*)(x + i8);
        float4 v1 = *(const float4*)(x + i8 + 4);
        o.s[0] = (short)f2b(v0.x); o.s[1] = (short)f2b(v0.y);
        o.s[2] = (short)f2b(v0.z); o.s[3] = (short)f2b(v0.w);
        o.s[4] = (short)f2b(v1.x); o.s[5] = (short)f2b(v1.y);
        o.s[6] = (short)f2b(v1.z); o.s[7] = (short)f2b(v1.w);
    } else {
        o.v = short8{0,0,0,0,0,0,0,0};
    }
    *(short8*)((short*)xb + i8) = o.v;
}

// ---------------------------------------------------------------------------
// Convert + transpose weight: w fp32 [K][N] -> wT bf16 [N][K].
// ---------------------------------------------------------------------------
__global__ __launch_bounds__(256)
void k_cvt_wT(const float* __restrict__ w, bf16* __restrict__ wT, int K, int N)
{
    __shared__ float t[32][33];
    int bn = blockIdx.x * 32, bk = blockIdx.y * 32;
    int tx = threadIdx.x & 31, ty = threadIdx.x >> 5;  // 32 x 8
    #pragma unroll
    for (int j = 0; j < 4; ++j)
        t[ty + j * 8][tx] = w[(size_t)(bk + ty + j * 8) * N + bn + tx];
    __syncthreads();
    #pragma unroll
    for (int j = 0; j < 4; ++j)
        wT[(size_t)(bn + ty + j * 8) * K + bk + tx] =
            __float2bfloat16(t[tx][ty + j * 8]);
}

// ---------------------------------------------------------------------------
// MFMA bf16 GEMM (m97 structure): C[M][N] = A[Mpad][512] @ Bt[N][512]^T
// 128x128 tile, BK=32, 256 threads (4 waves, 2x2), 4x4 16x16x32 frags/wave.
// ---------------------------------------------------------------------------
template <typename OutT>
__global__ __launch_bounds__(256)
void k_gemm_mfma(const bf16* __restrict__ A, const bf16* __restrict__ Bt,
                 OutT* __restrict__ C, int N, int Mlim)
{
    __shared__ short lds[8192];           // As [0..4095], Bs [4096..8191]
    short* As = lds;
    short* Bs = lds + 4096;

    const int tid = threadIdx.x;
    const int wave = tid >> 6, lane = tid & 63;
    const int bm = blockIdx.x * 128, bn = blockIdx.y * 128;

    const int flat0 = wave * 128 + lane;
    const int flat1 = flat0 + 64;
    const int rA0 = flat0 >> 2, pA0 = (flat0 & 3) * 8;
    const int rA1 = flat1 >> 2, pA1 = (flat1 & 3) * 8;

    const bf16* gA0 = A + (size_t)(bm + rA0) * 512 + pA0;
    const bf16* gA1 = A + (size_t)(bm + rA1) * 512 + pA1;
    const bf16* gB0 = Bt + (size_t)(bn + rA0) * 512 + pA0;
    const bf16* gB1 = Bt + (size_t)(bn + rA1) * 512 + pA1;
    short* lA0 = As + (wave * 2 + 0) * 512;
    short* lA1 = As + (wave * 2 + 1) * 512;
    short* lB0 = Bs + (wave * 2 + 0) * 512;
    short* lB1 = Bs + (wave * 2 + 1) * 512;

    const int m_base = (wave >> 1) * 64, n_base = (wave & 1) * 64;
    int aoff[4], boff[4];
    #pragma unroll
    for (int i = 0; i < 4; ++i) {
        aoff[i] = (m_base + i * 16 + (lane & 15)) * 32 + (lane >> 4) * 8;
        boff[i] = (n_base + i * 16 + (lane & 15)) * 32 + (lane >> 4) * 8;
    }

    f32x4 acc[4][4] = {};

    for (int k0 = 0; k0 < 512; k0 += 32) {
        gload_lds16(gA0, lA0);
        gload_lds16(gA1, lA1);
        gload_lds16(gB0, lB0);
        gload_lds16(gB1, lB1);
        gA0 += 32; gA1 += 32; gB0 += 32; gB1 += 32;
        __syncthreads();

        short8 a[4], b[4];
        #pragma unroll
        for (int i = 0; i < 4; ++i) a[i] = *(const short8*)(As + aoff[i]);
        #pragma unroll
        for (int i = 0; i < 4; ++i) b[i] = *(const short8*)(Bs + boff[i]);
        #pragma unroll
        for (int mi = 0; mi < 4; ++mi)
            #pragma unroll
            for (int ni = 0; ni < 4; ++ni)
                acc[mi][ni] = __builtin_amdgcn_mfma_f32_16x16x32_bf16(
                    a[mi], b[ni], acc[mi][ni], 0, 0, 0);
        __syncthreads();
    }

    #pragma unroll
    for (int mi = 0; mi < 4; ++mi) {
        #pragma unroll
        for (int ni = 0; ni < 4; ++ni) {
            int gr = bm + m_base + mi * 16 + (lane >> 4) * 4;
            int gc = bn + n_base + ni * 16 + (lane & 15);
            #pragma unroll
            for (int r = 0; r < 4; ++r) {
                if (gr + r < Mlim) {
                    float v = acc[mi][ni][r];
                    if constexpr (sizeof(OutT) == 2)
                        C[(size_t)(gr + r) * N + gc] = __float2bfloat16(v);
                    else
                        C[(size_t)(gr + r) * N + gc] = v;
                }
            }
        }
    }
}

// ---------------------------------------------------------------------------
// Window attention for tokens 1..4096. One block per (window, head, batch).
// ---------------------------------------------------------------------------
__global__ __launch_bounds__(256)
void k_attn_win(const bf16* __restrict__ qkv, bf16* __restrict__ aout)
{
    constexpr int SW = 68;
    __shared__ float smem[4 * 64 * SW];
    float* qT = smem;
    float* kT = smem + 64 * SW;
    float* vS = smem + 2 * 64 * SW;
    float* sS = smem + 3 * 64 * SW;
    float* pT = qT;

    const int n = blockIdx.x, h = blockIdx.y, b = blockIdx.z;
    const int tid = threadIdx.x;
    const bf16* base = qkv + ((size_t)b * Tc + 1 + (size_t)n * 64) * 1536 + h * 64;

    #pragma unroll
    for (int it = 0; it < 4; ++it) {
        int u = tid + it * 256;
        int row = u >> 4;
        int c4 = (u & 15) * 4;
        size_t roff = (size_t)row * 1536 + c4;
        ushort4 uq = *(const ushort4*)(base + roff);
        ushort4 uk = *(const ushort4*)(base + roff + 512);
        ushort4 uv = *(const ushort4*)(base + roff + 1024);
        qT[(c4 + 0) * SW + row] = bf2f(uq.x);
        qT[(c4 + 1) * SW + row] = bf2f(uq.y);
        qT[(c4 + 2) * SW + row] = bf2f(uq.z);
        qT[(c4 + 3) * SW + row] = bf2f(uq.w);
        kT[(c4 + 0) * SW + row] = bf2f(uk.x);
        kT[(c4 + 1) * SW + row] = bf2f(uk.y);
        kT[(c4 + 2) * SW + row] = bf2f(uk.z);
        kT[(c4 + 3) * SW + row] = bf2f(uk.w);
        float4 vv = make_float4(bf2f(uv.x), bf2f(uv.y), bf2f(uv.z), bf2f(uv.w));
        *(float4*)&vS[row * SW + c4] = vv;
    }
    __syncthreads();

    const int tx = tid & 15, ty = tid >> 4;

    float acc[4][4] = {};
    #pragma unroll
    for (int dd = 0; dd < 64; ++dd) {
        float4 a = *(const float4*)&qT[dd * SW + ty * 4];
        float4 bb = *(const float4*)&kT[dd * SW + tx * 4];
        float av[4] = {a.x, a.y, a.z, a.w};
        float bv[4] = {bb.x, bb.y, bb.z, bb.w};
        #pragma unroll
        for (int i = 0; i < 4; ++i)
            #pragma unroll
            for (int j = 0; j < 4; ++j)
                acc[i][j] = fmaf(av[i], bv[j], acc[i][j]);
    }
    #pragma unroll
    for (int i = 0; i < 4; ++i)
        #pragma unroll
        for (int j = 0; j < 4; ++j)
            sS[(ty * 4 + i) * SW + tx * 4 + j] = acc[i][j] * 0.125f;
    __syncthreads();

    if (tid < 64) {
        int r = tid;
        float m = -1e30f;
        for (int j = 0; j < 64; ++j) m = fmaxf(m, sS[r * SW + j]);
        float s = 0.f;
        for (int j = 0; j < 64; ++j) {
            float e = __expf(sS[r * SW + j] - m);
            sS[r * SW + j] = e;
            s += e;
        }
        float inv = 1.f / s;
        for (int j = 0; j < 64; ++j) pT[j * SW + r] = sS[r * SW + j] * inv;
    }
    __syncthreads();

    float o[4][4] = {};
    #pragma unroll
    for (int j = 0; j < 64; ++j) {
        float4 p = *(const float4*)&pT[j * SW + ty * 4];
        float4 v = *(const float4*)&vS[j * SW + tx * 4];
        float pv[4] = {p.x, p.y, p.z, p.w};
        float vv[4] = {v.x, v.y, v.z, v.w};
        #pragma unroll
        for (int i = 0; i < 4; ++i)
            #pragma unroll
            for (int jj = 0; jj < 4; ++jj)
                o[i][jj] = fmaf(pv[i], vv[jj], o[i][jj]);
    }

    #pragma unroll
    for (int i = 0; i < 4; ++i) {
        int t = 1 + n * 64 + ty * 4 + i;
        bf16* op = aout + ((size_t)b * Tc + t) * Dc + h * 64 + tx * 4;
        #pragma unroll
        for (int jj = 0; jj < 4; ++jj) op[jj] = __float2bfloat16(o[i][jj]);
    }
}

// ---------------------------------------------------------------------------
// Token-0 attention, split-K partial: one wave per (chunk c, head h, batch b).
// Each lane owns one key in the chunk. Writes partial {acc[64], m, s}.
// ---------------------------------------------------------------------------
__global__ __launch_bounds__(64)
void k_tok0_part(const bf16* __restrict__ qkv, float* __restrict__ part)
{
    const int c = blockIdx.x, h = blockIdx.y, b = blockIdx.z;
    const int lane = threadIdx.x;
    __shared__ float q0s[64];
    __shared__ float vS[64][65];
    __shared__ float pS[64];

    q0s[lane] = bf2f(*(const unsigned short*)
        (qkv + (size_t)b * Tc * 1536 + h * 64 + lane));
    __syncthreads();

    const int t = c * 64 + lane;
    const bool valid = t < Tc;
    float logit = -1e30f;
    if (valid) {
        const bf16* kp = qkv + ((size_t)b * Tc + t) * 1536 + 512 + h * 64;
        float l = 0.f;
        #pragma unroll
        for (int d4 = 0; d4 < 16; ++d4) {
            ushort4 ku = ((const ushort4*)kp)[d4];
            l = fmaf(q0s[d4 * 4 + 0], bf2f(ku.x), l);
            l = fmaf(q0s[d4 * 4 + 1], bf2f(ku.y), l);
            l = fmaf(q0s[d4 * 4 + 2], bf2f(ku.z), l);
            l = fmaf(q0s[d4 * 4 + 3], bf2f(ku.w), l);
        }
        logit = l * 0.125f;
        const bf16* vp = kp + 512;
        #pragma unroll
        for (int d4 = 0; d4 < 16; ++d4) {
            ushort4 vu = ((const ushort4*)vp)[d4];
            vS[lane][d4 * 4 + 0] = bf2f(vu.x);
            vS[lane][d4 * 4 + 1] = bf2f(vu.y);
            vS[lane][d4 * 4 + 2] = bf2f(vu.z);
            vS[lane][d4 * 4 + 3] = bf2f(vu.w);
        }
    } else {
        #pragma unroll
        for (int d = 0; d < 64; ++d) vS[lane][d] = 0.f;
    }

    float m = logit;
    #pragma unroll
    for (int off = 1; off < 64; off <<= 1) m = fmaxf(m, __shfl_xor(m, off));
    float p = valid ? __expf(logit - m) : 0.f;
    float s = p;
    #pragma unroll
    for (int off = 1; off < 64; off <<= 1) s += __shfl_xor(s, off);
    pS[lane] = p;
    __syncthreads();

    float o = 0.f;
    #pragma unroll
    for (int i = 0; i < 64; ++i) o = fmaf(pS[i], vS[i][lane], o);

    float* pout = part + ((size_t)(b * Hc + h) * NCh + c) * 66;
    pout[lane] = o;
    if (lane == 0) { pout[64] = m; pout[65] = s; }
}

// ---------------------------------------------------------------------------
// Token-0 reduce: combine NCh chunk partials per (b,h). One wave per (h,b).
// ---------------------------------------------------------------------------
__global__ __launch_bounds__(64)
void k_tok0_reduce(const float* __restrict__ part, bf16* __restrict__ aout)
{
    const int h = blockIdx.x, b = blockIdx.y;
    const int lane = threadIdx.x;
    const float* base = part + (size_t)(b * Hc + h) * NCh * 66;

    float M = -1e30f;
    for (int c = 0; c < NCh; ++c) M = fmaxf(M, base[c * 66 + 64]);

    float S = 0.f, o = 0.f;
    for (int c = 0; c < NCh; ++c) {
        const float* pp = base + c * 66;
        float w = __expf(pp[64] - M);
        S += pp[65] * w;
        o = fmaf(pp[lane], w, o);
    }
    aout[(size_t)b * Tc * Dc + h * 64 + lane] = __float2bfloat16(o / S);
}

// ---------------------------------------------------------------------------
extern "C" void kernel_launch(void* const* d_in, const int* in_sizes, int n_in,
                              void* d_out, int out_size, void* d_ws, size_t ws_size,
                              hipStream_t stream)
{
    const float* x     = (const float*)d_in[0];
    const float* w_qkv = (const float*)d_in[1];
    const float* w_out = (const float*)d_in[2];
    float* out = (float*)d_out;

    // ws layout (bf16 elems): qkv [Mpad*1536] | xa (xb & aout share) [Mpad*512]
    //                         | wqT [1536*512] | woT [512*512]
    // wqT region is reused for token-0 partials (dead after QKV GEMM):
    //   needs 8*8*65*66*4 B = 1.05 MB <= 1.57 MB.
    bf16* qkv = (bf16*)d_ws;
    bf16* xa  = qkv + (size_t)Mpad * 1536;
    bf16* wqT = xa  + (size_t)Mpad * 512;
    bf16* woT = wqT + (size_t)1536 * 512;
    float* part = (float*)wqT;

    // 1) conversions
    {
        int nblk = (int)(((size_t)Mpad * 512 / 8 + 255) / 256);
        k_cvt_x<<<nblk, 256, 0, stream>>>(x, xa);
    }
    k_cvt_wT<<<dim3(48, 16), 256, 0, stream>>>(w_qkv, wqT, 512, 1536);
    k_cvt_wT<<<dim3(16, 16), 256, 0, stream>>>(w_out, woT, 512, 512);

    // 2) qkv = x @ w_qkv  (MFMA)
    k_gemm_mfma<bf16><<<dim3(257, 12), 256, 0, stream>>>(xa, wqT, qkv, 1536, Mpad);

    // 3) attention: windows + split-K token-0 (wqT now dead -> partials there)
    k_attn_win<<<dim3(64, Hc, Bc), 256, 0, stream>>>(qkv, xa);
    k_tok0_part<<<dim3(NCh, Hc, Bc), dim3(64), 0, stream>>>(qkv, part);
    k_tok0_reduce<<<dim3(Hc, Bc), dim3(64), 0, stream>>>(part, xa);

    // 4) out = attn_out @ w_out  (MFMA, fp32 out)
    k_gemm_mfma<float><<<dim3(257, 4), 256, 0, stream>>>(xa, woT, out, 512, Mrows);
}

// Round 4
// 228.126 us; speedup vs baseline: 5.2239x; 1.2442x over previous
//
#include <hip/hip_runtime.h>
#include <hip/hip_bf16.h>
#include <cstdint>
#include <cstddef>

using bf16 = __hip_bfloat16;
using short8 = __attribute__((ext_vector_type(8))) short;
using f32x4  = __attribute__((ext_vector_type(4))) float;

constexpr int Bc = 8;
constexpr int Tc = 4097;
constexpr int Dc = 512;         // model dim
constexpr int Hc = 8;
constexpr int Mrows = Bc * Tc;  // 32776
constexpr int Mpad  = 32896;    // 257 * 128
constexpr int NCh = 65;         // token-0 key chunks (64 keys each)

__device__ __forceinline__ float bf2f(unsigned short u) {
    union { unsigned int i; float f; } v;
    v.i = ((unsigned int)u) << 16;
    return v.f;
}

__device__ __forceinline__ unsigned short f2b(float f) {
    union { float f; unsigned int i; } u; u.f = f;
    unsigned int r = u.i + 0x7FFFu + ((u.i >> 16) & 1u);  // RNE
    return (unsigned short)(r >> 16);
}

__device__ __forceinline__ void gload_lds16(const void* g, void* l) {
    __builtin_amdgcn_global_load_lds(
        (const __attribute__((address_space(1))) void*)g,
        (__attribute__((address_space(3))) void*)l, 16, 0, 0);
}

// ---------------------------------------------------------------------------
// Convert x (fp32 [Mrows][512]) -> bf16 [Mpad][512]; pad rows zeroed.
// ---------------------------------------------------------------------------
__global__ __launch_bounds__(256)
void k_cvt_x(const float* __restrict__ x, bf16* __restrict__ xb)
{
    size_t i8 = ((size_t)blockIdx.x * 256 + threadIdx.x) * 8;
    if (i8 >= (size_t)Mpad * 512) return;
    union { short s[8]; short8 v; } o;
    if (i8 < (size_t)Mrows * 512) {
        float4 v0 = *(const float4*)(x + i8);
        float4 v1 = *(const float4*)(x + i8 + 4);
        o.s[0] = (short)f2b(v0.x); o.s[1] = (short)f2b(v0.y);
        o.s[2] = (short)f2b(v0.z); o.s[3] = (short)f2b(v0.w);
        o.s[4] = (short)f2b(v1.x); o.s[5] = (short)f2b(v1.y);
        o.s[6] = (short)f2b(v1.z); o.s[7] = (short)f2b(v1.w);
    } else {
        o.v = short8{0,0,0,0,0,0,0,0};
    }
    *(short8*)((short*)xb + i8) = o.v;
}

// ---------------------------------------------------------------------------
// Convert + transpose weight: w fp32 [K][N] -> wT bf16 [N][K].
// ---------------------------------------------------------------------------
__global__ __launch_bounds__(256)
void k_cvt_wT(const float* __restrict__ w, bf16* __restrict__ wT, int K, int N)
{
    __shared__ float t[32][33];
    int bn = blockIdx.x * 32, bk = blockIdx.y * 32;
    int tx = threadIdx.x & 31, ty = threadIdx.x >> 5;  // 32 x 8
    #pragma unroll
    for (int j = 0; j < 4; ++j)
        t[ty + j * 8][tx] = w[(size_t)(bk + ty + j * 8) * N + bn + tx];
    __syncthreads();
    #pragma unroll
    for (int j = 0; j < 4; ++j)
        wT[(size_t)(bn + ty + j * 8) * K + bk + tx] =
            __float2bfloat16(t[tx][ty + j * 8]);
}

// ---------------------------------------------------------------------------
// MFMA bf16 GEMM (m97 structure): C[M][N] = A[Mpad][512] @ Bt[N][512]^T
// ---------------------------------------------------------------------------
template <typename OutT>
__global__ __launch_bounds__(256)
void k_gemm_mfma(const bf16* __restrict__ A, const bf16* __restrict__ Bt,
                 OutT* __restrict__ C, int N, int Mlim)
{
    __shared__ short lds[8192];           // As [0..4095], Bs [4096..8191]
    short* As = lds;
    short* Bs = lds + 4096;

    const int tid = threadIdx.x;
    const int wave = tid >> 6, lane = tid & 63;
    const int bm = blockIdx.x * 128, bn = blockIdx.y * 128;

    const int flat0 = wave * 128 + lane;
    const int flat1 = flat0 + 64;
    const int rA0 = flat0 >> 2, pA0 = (flat0 & 3) * 8;
    const int rA1 = flat1 >> 2, pA1 = (flat1 & 3) * 8;

    const bf16* gA0 = A + (size_t)(bm + rA0) * 512 + pA0;
    const bf16* gA1 = A + (size_t)(bm + rA1) * 512 + pA1;
    const bf16* gB0 = Bt + (size_t)(bn + rA0) * 512 + pA0;
    const bf16* gB1 = Bt + (size_t)(bn + rA1) * 512 + pA1;
    short* lA0 = As + (wave * 2 + 0) * 512;
    short* lA1 = As + (wave * 2 + 1) * 512;
    short* lB0 = Bs + (wave * 2 + 0) * 512;
    short* lB1 = Bs + (wave * 2 + 1) * 512;

    const int m_base = (wave >> 1) * 64, n_base = (wave & 1) * 64;
    int aoff[4], boff[4];
    #pragma unroll
    for (int i = 0; i < 4; ++i) {
        aoff[i] = (m_base + i * 16 + (lane & 15)) * 32 + (lane >> 4) * 8;
        boff[i] = (n_base + i * 16 + (lane & 15)) * 32 + (lane >> 4) * 8;
    }

    f32x4 acc[4][4] = {};

    for (int k0 = 0; k0 < 512; k0 += 32) {
        gload_lds16(gA0, lA0);
        gload_lds16(gA1, lA1);
        gload_lds16(gB0, lB0);
        gload_lds16(gB1, lB1);
        gA0 += 32; gA1 += 32; gB0 += 32; gB1 += 32;
        __syncthreads();

        short8 a[4], b[4];
        #pragma unroll
        for (int i = 0; i < 4; ++i) a[i] = *(const short8*)(As + aoff[i]);
        #pragma unroll
        for (int i = 0; i < 4; ++i) b[i] = *(const short8*)(Bs + boff[i]);
        #pragma unroll
        for (int mi = 0; mi < 4; ++mi)
            #pragma unroll
            for (int ni = 0; ni < 4; ++ni)
                acc[mi][ni] = __builtin_amdgcn_mfma_f32_16x16x32_bf16(
                    a[mi], b[ni], acc[mi][ni], 0, 0, 0);
        __syncthreads();
    }

    #pragma unroll
    for (int mi = 0; mi < 4; ++mi) {
        #pragma unroll
        for (int ni = 0; ni < 4; ++ni) {
            int gr = bm + m_base + mi * 16 + (lane >> 4) * 4;
            int gc = bn + n_base + ni * 16 + (lane & 15);
            #pragma unroll
            for (int r = 0; r < 4; ++r) {
                if (gr + r < Mlim) {
                    float v = acc[mi][ni][r];
                    if constexpr (sizeof(OutT) == 2)
                        C[(size_t)(gr + r) * N + gc] = __float2bfloat16(v);
                    else
                        C[(size_t)(gr + r) * N + gc] = v;
                }
            }
        }
    }
}

// ---------------------------------------------------------------------------
// Window attention (tokens 1..4096), MFMA version.
// One block (4 waves) per (window n, head h, batch b); wave w owns q-rows
// w*16..w*16+15. Q/K fragments load directly from global (each (row,h) slice
// is exactly one 128B line, fully consumed). LDS: P round-trip + V^T, both
// XOR-swizzled (byte ^= (row&7)<<4) to kill the stride-128B bank conflict.
// ---------------------------------------------------------------------------
__global__ __launch_bounds__(256)
void k_attn_win(const bf16* __restrict__ qkv, bf16* __restrict__ aout)
{
    __shared__ __attribute__((aligned(16))) unsigned short pS[64 * 64]; // [qrow][key] swz
    __shared__ __attribute__((aligned(16))) unsigned short vT[64 * 64]; // [d][key]   swz

    const int n = blockIdx.x, h = blockIdx.y, b = blockIdx.z;
    const int tid = threadIdx.x;
    const int wave = tid >> 6, lane = tid & 63;
    const int lo = lane & 15, g = lane >> 4;

    const bf16* base = qkv + ((size_t)b * Tc + 1 + (size_t)n * 64) * 1536 + h * 64;
    const bf16* kbase = base + 512;
    const bf16* vbase = base + 1024;

    // --- stage V transposed (swizzled): thread t -> key=t&63, d block (t>>6)*16
    {
        const int key = tid & 63;
        const int d0 = (tid >> 6) * 16;
        const bf16* vp = vbase + (size_t)key * 1536 + d0;
        ushort4 u[4];
        #pragma unroll
        for (int q = 0; q < 4; ++q) u[q] = *(const ushort4*)(vp + q * 4);
        const unsigned short vals[16] = {
            u[0].x, u[0].y, u[0].z, u[0].w, u[1].x, u[1].y, u[1].z, u[1].w,
            u[2].x, u[2].y, u[2].z, u[2].w, u[3].x, u[3].y, u[3].z, u[3].w };
        #pragma unroll
        for (int j = 0; j < 16; ++j) {
            int d = d0 + j;
            int byteoff = d * 128 + ((key * 2) ^ ((d & 7) << 4));
            *(unsigned short*)((char*)vT + byteoff) = vals[j];
        }
    }

    // --- Q fragments (rows wave*16+lo, k = g*8 + 32*s), direct global 16B
    short8 qf[2];
    {
        const bf16* qp = base + (size_t)(wave * 16 + lo) * 1536 + g * 8;
        qf[0] = *(const short8*)(qp);
        qf[1] = *(const short8*)(qp + 32);
    }

    // --- S = Q K^T * scale   (rows: this wave's 16; cols: all 64 keys)
    f32x4 sacc[4] = {};
    #pragma unroll
    for (int ni = 0; ni < 4; ++ni) {
        const bf16* kp = kbase + (size_t)(ni * 16 + lo) * 1536 + g * 8;
        short8 k0 = *(const short8*)(kp);
        short8 k1 = *(const short8*)(kp + 32);
        sacc[ni] = __builtin_amdgcn_mfma_f32_16x16x32_bf16(qf[0], k0, sacc[ni], 0, 0, 0);
        sacc[ni] = __builtin_amdgcn_mfma_f32_16x16x32_bf16(qf[1], k1, sacc[ni], 0, 0, 0);
    }

    __syncthreads();  // vT staging complete (placed after MFMA to overlap)

    // --- softmax over keys. Lane holds rows (g*4+r), cols ni*16+lo.
    float pv[4][4];   // [ni][r]
    float inv[4];     // per r
    #pragma unroll
    for (int r = 0; r < 4; ++r) {
        float m = fmaxf(fmaxf(sacc[0][r], sacc[1][r]),
                        fmaxf(sacc[2][r], sacc[3][r])) * 0.125f;
        m = fmaxf(m, __shfl_xor(m, 1));
        m = fmaxf(m, __shfl_xor(m, 2));
        m = fmaxf(m, __shfl_xor(m, 4));
        m = fmaxf(m, __shfl_xor(m, 8));
        float s = 0.f;
        #pragma unroll
        for (int ni = 0; ni < 4; ++ni) {
            float e = __expf(sacc[ni][r] * 0.125f - m);
            pv[ni][r] = e;
            s += e;
        }
        s += __shfl_xor(s, 1);
        s += __shfl_xor(s, 2);
        s += __shfl_xor(s, 4);
        s += __shfl_xor(s, 8);
        inv[r] = 1.f / s;
    }

    // --- write P (bf16) to LDS, swizzled [qrow][key]
    #pragma unroll
    for (int ni = 0; ni < 4; ++ni) {
        #pragma unroll
        for (int r = 0; r < 4; ++r) {
            int qrow = wave * 16 + g * 4 + r;
            int col = ni * 16 + lo;
            int byteoff = qrow * 128 + ((col * 2) ^ ((qrow & 7) << 4));
            *(unsigned short*)((char*)pS + byteoff) = f2b(pv[ni][r]);
        }
    }
    // P rows are wave-private; compiler's lgkmcnt ordering suffices, but the
    // read pattern below crosses lanes within the wave -> need wave-visible
    // LDS state: ds ops are wave-ordered per address only; use a cheap barrier.
    __syncthreads();

    // --- O = P V : A from pS (rows wave*16+lo), B from vT (cols d)
    f32x4 oacc[4] = {};
    #pragma unroll
    for (int s = 0; s < 2; ++s) {
        int arow = wave * 16 + lo;
        int abyte = arow * 128 + (((s * 32 + g * 8) * 2) ^ ((arow & 7) << 4));
        short8 pa = *(const short8*)((const char*)pS + abyte);
        #pragma unroll
        for (int nd = 0; nd < 4; ++nd) {
            int d = nd * 16 + lo;
            int bbyte = d * 128 + (((s * 32 + g * 8) * 2) ^ ((d & 7) << 4));
            short8 vb = *(const short8*)((const char*)vT + bbyte);
            oacc[nd] = __builtin_amdgcn_mfma_f32_16x16x32_bf16(pa, vb, oacc[nd], 0, 0, 0);
        }
    }

    // --- epilogue: scale rows by 1/sum, write bf16
    #pragma unroll
    for (int nd = 0; nd < 4; ++nd) {
        #pragma unroll
        for (int r = 0; r < 4; ++r) {
            int t = 1 + n * 64 + wave * 16 + g * 4 + r;
            aout[((size_t)b * Tc + t) * Dc + h * 64 + nd * 16 + lo] =
                __float2bfloat16(oacc[nd][r] * inv[r]);
        }
    }
}

// ---------------------------------------------------------------------------
// Token-0 attention, split-K partial: one wave per (chunk c, head h, batch b).
// ---------------------------------------------------------------------------
__global__ __launch_bounds__(64)
void k_tok0_part(const bf16* __restrict__ qkv, float* __restrict__ part)
{
    const int c = blockIdx.x, h = blockIdx.y, b = blockIdx.z;
    const int lane = threadIdx.x;
    __shared__ float q0s[64];
    __shared__ float vS[64][65];
    __shared__ float pSm[64];

    q0s[lane] = bf2f(*(const unsigned short*)
        (qkv + (size_t)b * Tc * 1536 + h * 64 + lane));
    __syncthreads();

    const int t = c * 64 + lane;
    const bool valid = t < Tc;
    float logit = -1e30f;
    if (valid) {
        const bf16* kp = qkv + ((size_t)b * Tc + t) * 1536 + 512 + h * 64;
        float l = 0.f;
        #pragma unroll
        for (int d4 = 0; d4 < 16; ++d4) {
            ushort4 ku = ((const ushort4*)kp)[d4];
            l = fmaf(q0s[d4 * 4 + 0], bf2f(ku.x), l);
            l = fmaf(q0s[d4 * 4 + 1], bf2f(ku.y), l);
            l = fmaf(q0s[d4 * 4 + 2], bf2f(ku.z), l);
            l = fmaf(q0s[d4 * 4 + 3], bf2f(ku.w), l);
        }
        logit = l * 0.125f;
        const bf16* vp = kp + 512;
        #pragma unroll
        for (int d4 = 0; d4 < 16; ++d4) {
            ushort4 vu = ((const ushort4*)vp)[d4];
            vS[lane][d4 * 4 + 0] = bf2f(vu.x);
            vS[lane][d4 * 4 + 1] = bf2f(vu.y);
            vS[lane][d4 * 4 + 2] = bf2f(vu.z);
            vS[lane][d4 * 4 + 3] = bf2f(vu.w);
        }
    } else {
        #pragma unroll
        for (int d = 0; d < 64; ++d) vS[lane][d] = 0.f;
    }

    float m = logit;
    #pragma unroll
    for (int off = 1; off < 64; off <<= 1) m = fmaxf(m, __shfl_xor(m, off));
    float p = valid ? __expf(logit - m) : 0.f;
    float s = p;
    #pragma unroll
    for (int off = 1; off < 64; off <<= 1) s += __shfl_xor(s, off);
    pSm[lane] = p;
    __syncthreads();

    float o = 0.f;
    #pragma unroll
    for (int i = 0; i < 64; ++i) o = fmaf(pSm[i], vS[i][lane], o);

    float* pout = part + ((size_t)(b * Hc + h) * NCh + c) * 66;
    pout[lane] = o;
    if (lane == 0) { pout[64] = m; pout[65] = s; }
}

// ---------------------------------------------------------------------------
// Token-0 reduce: combine NCh chunk partials per (b,h). One wave per (h,b).
// ---------------------------------------------------------------------------
__global__ __launch_bounds__(64)
void k_tok0_reduce(const float* __restrict__ part, bf16* __restrict__ aout)
{
    const int h = blockIdx.x, b = blockIdx.y;
    const int lane = threadIdx.x;
    const float* base = part + (size_t)(b * Hc + h) * NCh * 66;

    float M = -1e30f;
    for (int c = 0; c < NCh; ++c) M = fmaxf(M, base[c * 66 + 64]);

    float S = 0.f, o = 0.f;
    for (int c = 0; c < NCh; ++c) {
        const float* pp = base + c * 66;
        float w = __expf(pp[64] - M);
        S += pp[65] * w;
        o = fmaf(pp[lane], w, o);
    }
    aout[(size_t)b * Tc * Dc + h * 64 + lane] = __float2bfloat16(o / S);
}

// ---------------------------------------------------------------------------
extern "C" void kernel_launch(void* const* d_in, const int* in_sizes, int n_in,
                              void* d_out, int out_size, void* d_ws, size_t ws_size,
                              hipStream_t stream)
{
    const float* x     = (const float*)d_in[0];
    const float* w_qkv = (const float*)d_in[1];
    const float* w_out = (const float*)d_in[2];
    float* out = (float*)d_out;

    bf16* qkv = (bf16*)d_ws;
    bf16* xa  = qkv + (size_t)Mpad * 1536;
    bf16* wqT = xa  + (size_t)Mpad * 512;
    bf16* woT = wqT + (size_t)1536 * 512;
    float* part = (float*)wqT;   // reuses wqT (dead after QKV GEMM)

    // 1) conversions
    {
        int nblk = (int)(((size_t)Mpad * 512 / 8 + 255) / 256);
        k_cvt_x<<<nblk, 256, 0, stream>>>(x, xa);
    }
    k_cvt_wT<<<dim3(48, 16), 256, 0, stream>>>(w_qkv, wqT, 512, 1536);
    k_cvt_wT<<<dim3(16, 16), 256, 0, stream>>>(w_out, woT, 512, 512);

    // 2) qkv = x @ w_qkv  (MFMA)
    k_gemm_mfma<bf16><<<dim3(257, 12), 256, 0, stream>>>(xa, wqT, qkv, 1536, Mpad);

    // 3) attention: MFMA windows + split-K token-0
    k_attn_win<<<dim3(64, Hc, Bc), 256, 0, stream>>>(qkv, xa);
    k_tok0_part<<<dim3(NCh, Hc, Bc), dim3(64), 0, stream>>>(qkv, part);
    k_tok0_reduce<<<dim3(Hc, Bc), dim3(64), 0, stream>>>(part, xa);

    // 4) out = attn_out @ w_out  (MFMA, fp32 out)
    k_gemm_mfma<float><<<dim3(257, 4), 256, 0, stream>>>(xa, woT, out, 512, Mrows);
}

// Round 5
// 220.124 us; speedup vs baseline: 5.4138x; 1.0364x over previous
//
#include <hip/hip_runtime.h>
#include <hip/hip_bf16.h>
#include <cstdint>
#include <cstddef>

using bf16 = __hip_bfloat16;
using short8 = __attribute__((ext_vector_type(8))) short;
using f32x4  = __attribute__((ext_vector_type(4))) float;

constexpr int Bc = 8;
constexpr int Tc = 4097;
constexpr int Dc = 512;         // model dim
constexpr int Hc = 8;
constexpr int Mrows = Bc * Tc;  // 32776
constexpr int Mpad  = 32896;    // 257 * 128
constexpr int NCh = 65;         // token-0 key chunks (64 keys each)

__device__ __forceinline__ float bf2f(unsigned short u) {
    union { unsigned int i; float f; } v;
    v.i = ((unsigned int)u) << 16;
    return v.f;
}

__device__ __forceinline__ unsigned short f2b(float f) {
    union { float f; unsigned int i; } u; u.f = f;
    unsigned int r = u.i + 0x7FFFu + ((u.i >> 16) & 1u);  // RNE
    return (unsigned short)(r >> 16);
}

__device__ __forceinline__ void gload_lds16(const void* g, void* l) {
    __builtin_amdgcn_global_load_lds(
        (const __attribute__((address_space(1))) void*)g,
        (__attribute__((address_space(3))) void*)l, 16, 0, 0);
}

__device__ __forceinline__ short8 cvt8(float4 f0, float4 f1) {
    union { __hip_bfloat16 b; short s; } u;
    short8 r;
    u.b = __float2bfloat16(f0.x); r[0] = u.s;
    u.b = __float2bfloat16(f0.y); r[1] = u.s;
    u.b = __float2bfloat16(f0.z); r[2] = u.s;
    u.b = __float2bfloat16(f0.w); r[3] = u.s;
    u.b = __float2bfloat16(f1.x); r[4] = u.s;
    u.b = __float2bfloat16(f1.y); r[5] = u.s;
    u.b = __float2bfloat16(f1.z); r[6] = u.s;
    u.b = __float2bfloat16(f1.w); r[7] = u.s;
    return r;
}

// ---------------------------------------------------------------------------
// Convert + transpose weight: w fp32 [K][N] -> wT bf16 [N][K].
// ---------------------------------------------------------------------------
__global__ __launch_bounds__(256)
void k_cvt_wT(const float* __restrict__ w, bf16* __restrict__ wT, int K, int N)
{
    __shared__ float t[32][33];
    int bn = blockIdx.x * 32, bk = blockIdx.y * 32;
    int tx = threadIdx.x & 31, ty = threadIdx.x >> 5;  // 32 x 8
    #pragma unroll
    for (int j = 0; j < 4; ++j)
        t[ty + j * 8][tx] = w[(size_t)(bk + ty + j * 8) * N + bn + tx];
    __syncthreads();
    #pragma unroll
    for (int j = 0; j < 4; ++j)
        wT[(size_t)(bn + ty + j * 8) * K + bk + tx] =
            __float2bfloat16(t[tx][ty + j * 8]);
}

// ---------------------------------------------------------------------------
// MFMA bf16 GEMM, m97-style 2-phase, 128x128 tile, BK=32, 4 waves.
//  - AFP32: A operand staged fp32 (direct from x) + converted at frag-read.
//  - Operand-swapped MFMA => lane-contiguous N in epilogue (vector stores).
//  - Source-preswizzled LDS (linear global_load_lds dst + XOR'd ds_read).
//  - 1-D grid, m-tile-major, bijective XCD swizzle (m204) for A L2-reuse.
// ---------------------------------------------------------------------------
template <bool AFP32, typename OutT, int NT>
__global__ __launch_bounds__(256)
void k_gemm_mfma(const void* __restrict__ Aq, const bf16* __restrict__ Bt,
                 OutT* __restrict__ C, int Mlim)
{
    constexpr int N = NT * 128;
    __shared__ float AsF[AFP32 ? 4096 : 8];   // 16 KB (fp32 A tile 128x32)
    __shared__ short AsH[AFP32 ? 8 : 4096];   // 8 KB  (bf16 A tile)
    __shared__ short Bs[4096];                // 8 KB  (bf16 B tile)

    const int tid = threadIdx.x;
    const int wave = tid >> 6, lane = tid & 63;
    const int lo = lane & 15, g = lane >> 4;

    // bijective XCD swizzle (m204) on linear block id, m-tile-major
    const int nwg = 257 * NT;
    const int orig = blockIdx.x;
    const int qq = nwg >> 3, rr = nwg & 7;
    const int xc = orig & 7, o8 = orig >> 3;
    const int swz = (xc < rr ? xc * (qq + 1) : rr * (qq + 1) + (xc - rr) * qq) + o8;
    const int bm = (swz / NT) * 128, bn = (swz % NT) * 128;

    // ---- staging source pointers (source-preswizzled) ----
    const float* asF[4]; bool aokF[4];
    const bf16*  asH[2]; bool aokH[2];
    if constexpr (AFP32) {
        const float* A = (const float*)Aq;
        #pragma unroll
        for (int i = 0; i < 4; ++i) {
            int flat = i * 256 + tid, row = flat >> 3, p = flat & 7;
            asF[i] = A + (size_t)(bm + row) * 512 + ((p ^ (row & 7)) << 2);
            aokF[i] = (bm + row) < Mlim;
        }
    } else {
        const bf16* A = (const bf16*)Aq;
        #pragma unroll
        for (int i = 0; i < 2; ++i) {
            int flat = i * 256 + tid, row = flat >> 2, p = flat & 3;
            asH[i] = A + (size_t)(bm + row) * 512 + ((p ^ ((row >> 1) & 3)) << 3);
            aokH[i] = (bm + row) < Mlim;
        }
    }
    const bf16* bsrc[2];
    #pragma unroll
    for (int i = 0; i < 2; ++i) {
        int flat = i * 256 + tid, row = flat >> 2, p = flat & 3;
        bsrc[i] = Bt + (size_t)(bn + row) * 512 + ((p ^ ((row >> 1) & 3)) << 3);
    }

    // ---- fragment read offsets ----
    const int m_base = (wave >> 1) * 64, n_base = (wave & 1) * 64;
    int arow[4], brow[4];
    #pragma unroll
    for (int i = 0; i < 4; ++i) {
        arow[i] = m_base + i * 16 + lo;
        brow[i] = n_base + i * 16 + lo;
    }
    const int cA0 = (2 * g) ^ (lo & 7);         // fp32 A float4-chunk slots
    const int cA1 = (2 * g + 1) ^ (lo & 7);
    const int sH  = g ^ ((lo >> 1) & 3);        // bf16 16B-chunk slot

    f32x4 acc[4][4] = {};

    for (int k0 = 0; k0 < 512; k0 += 32) {
        if constexpr (AFP32) {
            #pragma unroll
            for (int i = 0; i < 4; ++i) {
                if (aokF[i]) gload_lds16(asF[i], AsF + (i * 256 + tid) * 4);
                asF[i] += 32;
            }
        } else {
            #pragma unroll
            for (int i = 0; i < 2; ++i) {
                if (aokH[i]) gload_lds16(asH[i], AsH + (i * 256 + tid) * 8);
                asH[i] += 32;
            }
        }
        #pragma unroll
        for (int i = 0; i < 2; ++i) {
            gload_lds16(bsrc[i], Bs + (i * 256 + tid) * 8);
            bsrc[i] += 32;
        }
        __syncthreads();

        short8 a[4], b[4];
        if constexpr (AFP32) {
            #pragma unroll
            for (int mi = 0; mi < 4; ++mi) {
                const float* ap = AsF + arow[mi] * 32;
                float4 f0 = *(const float4*)(ap + cA0 * 4);
                float4 f1 = *(const float4*)(ap + cA1 * 4);
                a[mi] = cvt8(f0, f1);
            }
        } else {
            #pragma unroll
            for (int mi = 0; mi < 4; ++mi)
                a[mi] = *(const short8*)(AsH + arow[mi] * 32 + sH * 8);
        }
        #pragma unroll
        for (int ni = 0; ni < 4; ++ni)
            b[ni] = *(const short8*)(Bs + brow[ni] * 32 + sH * 8);

        // operand-swapped: D n-dim on (lane>>4)*4+r, m-dim on lane&15
        #pragma unroll
        for (int mi = 0; mi < 4; ++mi)
            #pragma unroll
            for (int ni = 0; ni < 4; ++ni)
                acc[mi][ni] = __builtin_amdgcn_mfma_f32_16x16x32_bf16(
                    b[ni], a[mi], acc[mi][ni], 0, 0, 0);
        __syncthreads();
    }

    // ---- epilogue: m = lane&15 dim, n = (lane>>4)*4 + r => vector stores ----
    #pragma unroll
    for (int mi = 0; mi < 4; ++mi) {
        int m = bm + m_base + mi * 16 + lo;
        if (m < Mlim) {
            #pragma unroll
            for (int ni = 0; ni < 4; ++ni) {
                int n = bn + n_base + ni * 16 + g * 4;
                if constexpr (sizeof(OutT) == 2) {
                    ushort4 o = { f2b(acc[mi][ni][0]), f2b(acc[mi][ni][1]),
                                  f2b(acc[mi][ni][2]), f2b(acc[mi][ni][3]) };
                    *(ushort4*)((bf16*)C + (size_t)m * N + n) = o;
                } else {
                    float4 o = { acc[mi][ni][0], acc[mi][ni][1],
                                 acc[mi][ni][2], acc[mi][ni][3] };
                    *(float4*)((float*)C + (size_t)m * N + n) = o;
                }
            }
        }
    }
}

// ---------------------------------------------------------------------------
// Window attention (tokens 1..4096), MFMA version (unchanged from r3).
// ---------------------------------------------------------------------------
__global__ __launch_bounds__(256)
void k_attn_win(const bf16* __restrict__ qkv, bf16* __restrict__ aout)
{
    __shared__ __attribute__((aligned(16))) unsigned short pS[64 * 64];
    __shared__ __attribute__((aligned(16))) unsigned short vT[64 * 64];

    const int n = blockIdx.x, h = blockIdx.y, b = blockIdx.z;
    const int tid = threadIdx.x;
    const int wave = tid >> 6, lane = tid & 63;
    const int lo = lane & 15, g = lane >> 4;

    const bf16* base = qkv + ((size_t)b * Tc + 1 + (size_t)n * 64) * 1536 + h * 64;
    const bf16* kbase = base + 512;
    const bf16* vbase = base + 1024;

    {
        const int key = tid & 63;
        const int d0 = (tid >> 6) * 16;
        const bf16* vp = vbase + (size_t)key * 1536 + d0;
        ushort4 u[4];
        #pragma unroll
        for (int q = 0; q < 4; ++q) u[q] = *(const ushort4*)(vp + q * 4);
        const unsigned short vals[16] = {
            u[0].x, u[0].y, u[0].z, u[0].w, u[1].x, u[1].y, u[1].z, u[1].w,
            u[2].x, u[2].y, u[2].z, u[2].w, u[3].x, u[3].y, u[3].z, u[3].w };
        #pragma unroll
        for (int j = 0; j < 16; ++j) {
            int d = d0 + j;
            int byteoff = d * 128 + ((key * 2) ^ ((d & 7) << 4));
            *(unsigned short*)((char*)vT + byteoff) = vals[j];
        }
    }

    short8 qf[2];
    {
        const bf16* qp = base + (size_t)(wave * 16 + lo) * 1536 + g * 8;
        qf[0] = *(const short8*)(qp);
        qf[1] = *(const short8*)(qp + 32);
    }

    f32x4 sacc[4] = {};
    #pragma unroll
    for (int ni = 0; ni < 4; ++ni) {
        const bf16* kp = kbase + (size_t)(ni * 16 + lo) * 1536 + g * 8;
        short8 k0 = *(const short8*)(kp);
        short8 k1 = *(const short8*)(kp + 32);
        sacc[ni] = __builtin_amdgcn_mfma_f32_16x16x32_bf16(qf[0], k0, sacc[ni], 0, 0, 0);
        sacc[ni] = __builtin_amdgcn_mfma_f32_16x16x32_bf16(qf[1], k1, sacc[ni], 0, 0, 0);
    }

    __syncthreads();

    float pv[4][4];
    float inv[4];
    #pragma unroll
    for (int r = 0; r < 4; ++r) {
        float m = fmaxf(fmaxf(sacc[0][r], sacc[1][r]),
                        fmaxf(sacc[2][r], sacc[3][r])) * 0.125f;
        m = fmaxf(m, __shfl_xor(m, 1));
        m = fmaxf(m, __shfl_xor(m, 2));
        m = fmaxf(m, __shfl_xor(m, 4));
        m = fmaxf(m, __shfl_xor(m, 8));
        float s = 0.f;
        #pragma unroll
        for (int ni = 0; ni < 4; ++ni) {
            float e = __expf(sacc[ni][r] * 0.125f - m);
            pv[ni][r] = e;
            s += e;
        }
        s += __shfl_xor(s, 1);
        s += __shfl_xor(s, 2);
        s += __shfl_xor(s, 4);
        s += __shfl_xor(s, 8);
        inv[r] = 1.f / s;
    }

    #pragma unroll
    for (int ni = 0; ni < 4; ++ni) {
        #pragma unroll
        for (int r = 0; r < 4; ++r) {
            int qrow = wave * 16 + g * 4 + r;
            int col = ni * 16 + lo;
            int byteoff = qrow * 128 + ((col * 2) ^ ((qrow & 7) << 4));
            *(unsigned short*)((char*)pS + byteoff) = f2b(pv[ni][r]);
        }
    }
    __syncthreads();

    f32x4 oacc[4] = {};
    #pragma unroll
    for (int s = 0; s < 2; ++s) {
        int arow2 = wave * 16 + lo;
        int abyte = arow2 * 128 + (((s * 32 + g * 8) * 2) ^ ((arow2 & 7) << 4));
        short8 pa = *(const short8*)((const char*)pS + abyte);
        #pragma unroll
        for (int nd = 0; nd < 4; ++nd) {
            int d = nd * 16 + lo;
            int bbyte = d * 128 + (((s * 32 + g * 8) * 2) ^ ((d & 7) << 4));
            short8 vb = *(const short8*)((const char*)vT + bbyte);
            oacc[nd] = __builtin_amdgcn_mfma_f32_16x16x32_bf16(pa, vb, oacc[nd], 0, 0, 0);
        }
    }

    #pragma unroll
    for (int nd = 0; nd < 4; ++nd) {
        #pragma unroll
        for (int r = 0; r < 4; ++r) {
            int t = 1 + n * 64 + wave * 16 + g * 4 + r;
            aout[((size_t)b * Tc + t) * Dc + h * 64 + nd * 16 + lo] =
                __float2bfloat16(oacc[nd][r] * inv[r]);
        }
    }
}

// ---------------------------------------------------------------------------
// Token-0 attention, split-K partial (unchanged from r3).
// ---------------------------------------------------------------------------
__global__ __launch_bounds__(64)
void k_tok0_part(const bf16* __restrict__ qkv, float* __restrict__ part)
{
    const int c = blockIdx.x, h = blockIdx.y, b = blockIdx.z;
    const int lane = threadIdx.x;
    __shared__ float q0s[64];
    __shared__ float vS[64][65];
    __shared__ float pSm[64];

    q0s[lane] = bf2f(*(const unsigned short*)
        (qkv + (size_t)b * Tc * 1536 + h * 64 + lane));
    __syncthreads();

    const int t = c * 64 + lane;
    const bool valid = t < Tc;
    float logit = -1e30f;
    if (valid) {
        const bf16* kp = qkv + ((size_t)b * Tc + t) * 1536 + 512 + h * 64;
        float l = 0.f;
        #pragma unroll
        for (int d4 = 0; d4 < 16; ++d4) {
            ushort4 ku = ((const ushort4*)kp)[d4];
            l = fmaf(q0s[d4 * 4 + 0], bf2f(ku.x), l);
            l = fmaf(q0s[d4 * 4 + 1], bf2f(ku.y), l);
            l = fmaf(q0s[d4 * 4 + 2], bf2f(ku.z), l);
            l = fmaf(q0s[d4 * 4 + 3], bf2f(ku.w), l);
        }
        logit = l * 0.125f;
        const bf16* vp = kp + 512;
        #pragma unroll
        for (int d4 = 0; d4 < 16; ++d4) {
            ushort4 vu = ((const ushort4*)vp)[d4];
            vS[lane][d4 * 4 + 0] = bf2f(vu.x);
            vS[lane][d4 * 4 + 1] = bf2f(vu.y);
            vS[lane][d4 * 4 + 2] = bf2f(vu.z);
            vS[lane][d4 * 4 + 3] = bf2f(vu.w);
        }
    } else {
        #pragma unroll
        for (int d = 0; d < 64; ++d) vS[lane][d] = 0.f;
    }

    float m = logit;
    #pragma unroll
    for (int off = 1; off < 64; off <<= 1) m = fmaxf(m, __shfl_xor(m, off));
    float p = valid ? __expf(logit - m) : 0.f;
    float s = p;
    #pragma unroll
    for (int off = 1; off < 64; off <<= 1) s += __shfl_xor(s, off);
    pSm[lane] = p;
    __syncthreads();

    float o = 0.f;
    #pragma unroll
    for (int i = 0; i < 64; ++i) o = fmaf(pSm[i], vS[i][lane], o);

    float* pout = part + ((size_t)(b * Hc + h) * NCh + c) * 66;
    pout[lane] = o;
    if (lane == 0) { pout[64] = m; pout[65] = s; }
}

// ---------------------------------------------------------------------------
// Token-0 reduce (unchanged from r3).
// ---------------------------------------------------------------------------
__global__ __launch_bounds__(64)
void k_tok0_reduce(const float* __restrict__ part, bf16* __restrict__ aout)
{
    const int h = blockIdx.x, b = blockIdx.y;
    const int lane = threadIdx.x;
    const float* base = part + (size_t)(b * Hc + h) * NCh * 66;

    float M = -1e30f;
    for (int c = 0; c < NCh; ++c) M = fmaxf(M, base[c * 66 + 64]);

    float S = 0.f, o = 0.f;
    for (int c = 0; c < NCh; ++c) {
        const float* pp = base + c * 66;
        float w = __expf(pp[64] - M);
        S += pp[65] * w;
        o = fmaf(pp[lane], w, o);
    }
    aout[(size_t)b * Tc * Dc + h * 64 + lane] = __float2bfloat16(o / S);
}

// ---------------------------------------------------------------------------
extern "C" void kernel_launch(void* const* d_in, const int* in_sizes, int n_in,
                              void* d_out, int out_size, void* d_ws, size_t ws_size,
                              hipStream_t stream)
{
    const float* x     = (const float*)d_in[0];
    const float* w_qkv = (const float*)d_in[1];
    const float* w_out = (const float*)d_in[2];
    float* out = (float*)d_out;

    // ws layout (bf16 elems): qkv [Mpad*1536] | aout [Mpad*512]
    //                         | wqT [1536*512] | woT [512*512]
    // token-0 partials reuse wqT (dead after QKV GEMM): 1.05 MB <= 1.57 MB.
    bf16* qkv  = (bf16*)d_ws;
    bf16* aout = qkv  + (size_t)Mpad * 1536;
    bf16* wqT  = aout + (size_t)Mpad * 512;
    bf16* woT  = wqT  + (size_t)1536 * 512;
    float* part = (float*)wqT;

    // 1) weight conversions (x conversion fused into QKV GEMM staging)
    k_cvt_wT<<<dim3(48, 16), 256, 0, stream>>>(w_qkv, wqT, 512, 1536);
    k_cvt_wT<<<dim3(16, 16), 256, 0, stream>>>(w_out, woT, 512, 512);

    // 2) qkv = x @ w_qkv  (MFMA; A staged fp32 directly from x)
    k_gemm_mfma<true, bf16, 12><<<257 * 12, 256, 0, stream>>>(
        x, wqT, qkv, Mrows);

    // 3) attention: MFMA windows + split-K token-0
    k_attn_win<<<dim3(64, Hc, Bc), 256, 0, stream>>>(qkv, aout);
    k_tok0_part<<<dim3(NCh, Hc, Bc), dim3(64), 0, stream>>>(qkv, part);
    k_tok0_reduce<<<dim3(Hc, Bc), dim3(64), 0, stream>>>(part, aout);

    // 4) out = attn_out @ w_out  (MFMA, fp32 out)
    k_gemm_mfma<false, float, 4><<<257 * 4, 256, 0, stream>>>(
        aout, woT, out, Mrows);
}

// Round 6
// 215.188 us; speedup vs baseline: 5.5380x; 1.0229x over previous
//
#include <hip/hip_runtime.h>
#include <hip/hip_bf16.h>
#include <cstdint>
#include <cstddef>

using bf16 = __hip_bfloat16;
using short8 = __attribute__((ext_vector_type(8))) short;
using f32x4  = __attribute__((ext_vector_type(4))) float;

constexpr int Bc = 8;
constexpr int Tc = 4097;
constexpr int Dc = 512;         // model dim
constexpr int Hc = 8;
constexpr int Mrows = Bc * Tc;  // 32776
constexpr int Mpad2 = 33024;    // 129 * 256 (for 256-row GEMM tiles)
constexpr int NCh = 65;         // token-0 key chunks (64 keys each)

__device__ __forceinline__ float bf2f(unsigned short u) {
    union { unsigned int i; float f; } v;
    v.i = ((unsigned int)u) << 16;
    return v.f;
}

__device__ __forceinline__ unsigned short f2b(float f) {
    union { float f; unsigned int i; } u; u.f = f;
    unsigned int r = u.i + 0x7FFFu + ((u.i >> 16) & 1u);  // RNE
    return (unsigned short)(r >> 16);
}

__device__ __forceinline__ void gload_lds16(const void* g, void* l) {
    __builtin_amdgcn_global_load_lds(
        (const __attribute__((address_space(1))) void*)g,
        (__attribute__((address_space(3))) void*)l, 16, 0, 0);
}

// ---------------------------------------------------------------------------
// Convert x (fp32 [Mrows][512]) -> bf16 [Mpad2][512]; pad rows zeroed.
// ---------------------------------------------------------------------------
__global__ __launch_bounds__(256)
void k_cvt_x(const float* __restrict__ x, bf16* __restrict__ xb)
{
    size_t i8 = ((size_t)blockIdx.x * 256 + threadIdx.x) * 8;
    if (i8 >= (size_t)Mpad2 * 512) return;
    union { short s[8]; short8 v; } o;
    if (i8 < (size_t)Mrows * 512) {
        float4 v0 = *(const float4*)(x + i8);
        float4 v1 = *(const float4*)(x + i8 + 4);
        o.s[0] = (short)f2b(v0.x); o.s[1] = (short)f2b(v0.y);
        o.s[2] = (short)f2b(v0.z); o.s[3] = (short)f2b(v0.w);
        o.s[4] = (short)f2b(v1.x); o.s[5] = (short)f2b(v1.y);
        o.s[6] = (short)f2b(v1.z); o.s[7] = (short)f2b(v1.w);
    } else {
        o.v = short8{0,0,0,0,0,0,0,0};
    }
    *(short8*)((short*)xb + i8) = o.v;
}

// ---------------------------------------------------------------------------
// Convert + transpose weight: w fp32 [K][N] -> wT bf16 [N][K].
// ---------------------------------------------------------------------------
__global__ __launch_bounds__(256)
void k_cvt_wT(const float* __restrict__ w, bf16* __restrict__ wT, int K, int N)
{
    __shared__ float t[32][33];
    int bn = blockIdx.x * 32, bk = blockIdx.y * 32;
    int tx = threadIdx.x & 31, ty = threadIdx.x >> 5;  // 32 x 8
    #pragma unroll
    for (int j = 0; j < 4; ++j)
        t[ty + j * 8][tx] = w[(size_t)(bk + ty + j * 8) * N + bn + tx];
    __syncthreads();
    #pragma unroll
    for (int j = 0; j < 4; ++j)
        wT[(size_t)(bn + ty + j * 8) * K + bk + tx] =
            __float2bfloat16(t[tx][ty + j * 8]);
}

// ---------------------------------------------------------------------------
// 256x256-tile, BK=64, 8-wave (2Mx4N) double-buffered MFMA GEMM with counted
// vmcnt pipeline (raw s_barrier; __syncthreads would drain vmcnt(0)).
//   C[M][NT*256] = A[.][512] @ Bt[NT*256][512]^T
// LDS: 2 bufs x (A 256x64 + B 256x64) bf16 = 128 KiB.
// Swizzle (conflict-free ds_read_b128): 16B chunk (row, ck) stored at LDS
// col (ck+row)&7; staged via linear global_load_lds dest + rotated SOURCE.
// ---------------------------------------------------------------------------
template <typename OutT, int NT>
__global__ __launch_bounds__(512)
void k_gemm_8w(const bf16* __restrict__ A, const bf16* __restrict__ Bt,
               OutT* __restrict__ C, int Mlim)
{
    constexpr int N = NT * 256;
    __shared__ short lds[65536];   // [buf][A:16384 | B:16384] shorts

    const int tid = threadIdx.x;
    const int lane = tid & 63, wave = tid >> 6;
    const int lo = lane & 15, g = lane >> 4;
    const int wr = wave >> 2, wc = wave & 3;

    // bijective XCD swizzle (m204), m-tile-major linear id
    const int nwg = 129 * NT;
    const int orig = blockIdx.x;
    const int qq = nwg >> 3, rr = nwg & 7;
    const int xc = orig & 7, o8 = orig >> 3;
    const int swz = (xc < rr ? xc * (qq + 1) : rr * (qq + 1) + (xc - rr) * qq) + o8;
    const int bm = (swz / NT) * 256, bn = (swz % NT) * 256;

    // ---- staging pointers: thread handles chunks d = i*512+tid ----
    const bf16* aSrc[4]; const bf16* bSrc[4];
    int aDst[4], bDst[4];
    #pragma unroll
    for (int i = 0; i < 4; ++i) {
        int d = i * 512 + tid;
        int row = d >> 3, c = d & 7;
        int ck = (c - row) & 7;                 // rotated source chunk
        aSrc[i] = A  + (size_t)(bm + row) * 512 + ck * 8;
        bSrc[i] = Bt + (size_t)(bn + row) * 512 + ck * 8;
        aDst[i] = d * 8;                        // linear LDS (shorts)
        bDst[i] = 16384 + d * 8;
    }

    auto STAGE = [&](int kt) {
        const int bb = (kt & 1) * 32768;
        #pragma unroll
        for (int i = 0; i < 4; ++i)
            gload_lds16(aSrc[i] + kt * 64, lds + bb + aDst[i]);
        #pragma unroll
        for (int i = 0; i < 4; ++i)
            gload_lds16(bSrc[i] + kt * 64, lds + bb + bDst[i]);
    };

    // ---- fragment read constants ----
    const int colk[2] = { (g + (lo & 7)) & 7, (g + 4 + (lo & 7)) & 7 };
    const int arow0 = wr * 128 + lo;
    const int brow0 = wc * 64 + lo;

    f32x4 acc[8][4] = {};

    STAGE(0);
    STAGE(1);
    asm volatile("s_waitcnt vmcnt(8)" ::: "memory");   // K-tile 0 landed
    __builtin_amdgcn_s_barrier();

    for (int t = 0; t < 8; ++t) {
        const short* bufA = lds + (t & 1) * 32768;
        const short* bufB = bufA + 16384;

        #pragma unroll
        for (int ks = 0; ks < 2; ++ks) {
            const int col = colk[ks];
            short8 af[8], bfr[4];
            #pragma unroll
            for (int mi = 0; mi < 8; ++mi)
                af[mi] = *(const short8*)(bufA + (arow0 + mi * 16) * 64 + col * 8);
            #pragma unroll
            for (int ni = 0; ni < 4; ++ni)
                bfr[ni] = *(const short8*)(bufB + (brow0 + ni * 16) * 64 + col * 8);
            __builtin_amdgcn_s_setprio(1);
            #pragma unroll
            for (int mi = 0; mi < 8; ++mi)
                #pragma unroll
                for (int ni = 0; ni < 4; ++ni)
                    acc[mi][ni] = __builtin_amdgcn_mfma_f32_16x16x32_bf16(
                        bfr[ni], af[mi], acc[mi][ni], 0, 0, 0);
            __builtin_amdgcn_s_setprio(0);
        }

        // all waves done reading buf[t&1] before its next overwrite
        asm volatile("s_waitcnt lgkmcnt(0)" ::: "memory");
        __builtin_amdgcn_s_barrier();
        if (t < 6) {
            STAGE(t + 2);                                 // into buf[t&1]
            asm volatile("s_waitcnt vmcnt(8)" ::: "memory");  // K-tile t+1 ready
            __builtin_amdgcn_s_barrier();
        } else if (t == 6) {
            asm volatile("s_waitcnt vmcnt(0)" ::: "memory");  // K-tile 7 ready
            __builtin_amdgcn_s_barrier();
        }
    }

    // ---- epilogue: m = lane&15 dim, n = (lane>>4)*4 + r (vector stores) ----
    #pragma unroll
    for (int mi = 0; mi < 8; ++mi) {
        int m = bm + wr * 128 + mi * 16 + lo;
        if (m < Mlim) {
            #pragma unroll
            for (int ni = 0; ni < 4; ++ni) {
                int n = bn + wc * 64 + ni * 16 + g * 4;
                if constexpr (sizeof(OutT) == 2) {
                    ushort4 o = { f2b(acc[mi][ni][0]), f2b(acc[mi][ni][1]),
                                  f2b(acc[mi][ni][2]), f2b(acc[mi][ni][3]) };
                    *(ushort4*)((bf16*)C + (size_t)m * N + n) = o;
                } else {
                    float4 o = { acc[mi][ni][0], acc[mi][ni][1],
                                 acc[mi][ni][2], acc[mi][ni][3] };
                    *(float4*)((float*)C + (size_t)m * N + n) = o;
                }
            }
        }
    }
}

// ---------------------------------------------------------------------------
// Window attention (tokens 1..4096), MFMA version (unchanged from r3).
// ---------------------------------------------------------------------------
__global__ __launch_bounds__(256)
void k_attn_win(const bf16* __restrict__ qkv, bf16* __restrict__ aout)
{
    __shared__ __attribute__((aligned(16))) unsigned short pS[64 * 64];
    __shared__ __attribute__((aligned(16))) unsigned short vT[64 * 64];

    const int n = blockIdx.x, h = blockIdx.y, b = blockIdx.z;
    const int tid = threadIdx.x;
    const int wave = tid >> 6, lane = tid & 63;
    const int lo = lane & 15, g = lane >> 4;

    const bf16* base = qkv + ((size_t)b * Tc + 1 + (size_t)n * 64) * 1536 + h * 64;
    const bf16* kbase = base + 512;
    const bf16* vbase = base + 1024;

    {
        const int key = tid & 63;
        const int d0 = (tid >> 6) * 16;
        const bf16* vp = vbase + (size_t)key * 1536 + d0;
        ushort4 u[4];
        #pragma unroll
        for (int q = 0; q < 4; ++q) u[q] = *(const ushort4*)(vp + q * 4);
        const unsigned short vals[16] = {
            u[0].x, u[0].y, u[0].z, u[0].w, u[1].x, u[1].y, u[1].z, u[1].w,
            u[2].x, u[2].y, u[2].z, u[2].w, u[3].x, u[3].y, u[3].z, u[3].w };
        #pragma unroll
        for (int j = 0; j < 16; ++j) {
            int d = d0 + j;
            int byteoff = d * 128 + ((key * 2) ^ ((d & 7) << 4));
            *(unsigned short*)((char*)vT + byteoff) = vals[j];
        }
    }

    short8 qf[2];
    {
        const bf16* qp = base + (size_t)(wave * 16 + lo) * 1536 + g * 8;
        qf[0] = *(const short8*)(qp);
        qf[1] = *(const short8*)(qp + 32);
    }

    f32x4 sacc[4] = {};
    #pragma unroll
    for (int ni = 0; ni < 4; ++ni) {
        const bf16* kp = kbase + (size_t)(ni * 16 + lo) * 1536 + g * 8;
        short8 k0 = *(const short8*)(kp);
        short8 k1 = *(const short8*)(kp + 32);
        sacc[ni] = __builtin_amdgcn_mfma_f32_16x16x32_bf16(qf[0], k0, sacc[ni], 0, 0, 0);
        sacc[ni] = __builtin_amdgcn_mfma_f32_16x16x32_bf16(qf[1], k1, sacc[ni], 0, 0, 0);
    }

    __syncthreads();

    float pv[4][4];
    float inv[4];
    #pragma unroll
    for (int r = 0; r < 4; ++r) {
        float m = fmaxf(fmaxf(sacc[0][r], sacc[1][r]),
                        fmaxf(sacc[2][r], sacc[3][r])) * 0.125f;
        m = fmaxf(m, __shfl_xor(m, 1));
        m = fmaxf(m, __shfl_xor(m, 2));
        m = fmaxf(m, __shfl_xor(m, 4));
        m = fmaxf(m, __shfl_xor(m, 8));
        float s = 0.f;
        #pragma unroll
        for (int ni = 0; ni < 4; ++ni) {
            float e = __expf(sacc[ni][r] * 0.125f - m);
            pv[ni][r] = e;
            s += e;
        }
        s += __shfl_xor(s, 1);
        s += __shfl_xor(s, 2);
        s += __shfl_xor(s, 4);
        s += __shfl_xor(s, 8);
        inv[r] = 1.f / s;
    }

    #pragma unroll
    for (int ni = 0; ni < 4; ++ni) {
        #pragma unroll
        for (int r = 0; r < 4; ++r) {
            int qrow = wave * 16 + g * 4 + r;
            int col = ni * 16 + lo;
            int byteoff = qrow * 128 + ((col * 2) ^ ((qrow & 7) << 4));
            *(unsigned short*)((char*)pS + byteoff) = f2b(pv[ni][r]);
        }
    }
    __syncthreads();

    f32x4 oacc[4] = {};
    #pragma unroll
    for (int s = 0; s < 2; ++s) {
        int arow2 = wave * 16 + lo;
        int abyte = arow2 * 128 + (((s * 32 + g * 8) * 2) ^ ((arow2 & 7) << 4));
        short8 pa = *(const short8*)((const char*)pS + abyte);
        #pragma unroll
        for (int nd = 0; nd < 4; ++nd) {
            int d = nd * 16 + lo;
            int bbyte = d * 128 + (((s * 32 + g * 8) * 2) ^ ((d & 7) << 4));
            short8 vb = *(const short8*)((const char*)vT + bbyte);
            oacc[nd] = __builtin_amdgcn_mfma_f32_16x16x32_bf16(pa, vb, oacc[nd], 0, 0, 0);
        }
    }

    #pragma unroll
    for (int nd = 0; nd < 4; ++nd) {
        #pragma unroll
        for (int r = 0; r < 4; ++r) {
            int t = 1 + n * 64 + wave * 16 + g * 4 + r;
            aout[((size_t)b * Tc + t) * Dc + h * 64 + nd * 16 + lo] =
                __float2bfloat16(oacc[nd][r] * inv[r]);
        }
    }
}

// ---------------------------------------------------------------------------
// Token-0 attention, split-K partial (unchanged).
// ---------------------------------------------------------------------------
__global__ __launch_bounds__(64)
void k_tok0_part(const bf16* __restrict__ qkv, float* __restrict__ part)
{
    const int c = blockIdx.x, h = blockIdx.y, b = blockIdx.z;
    const int lane = threadIdx.x;
    __shared__ float q0s[64];
    __shared__ float vS[64][65];
    __shared__ float pSm[64];

    q0s[lane] = bf2f(*(const unsigned short*)
        (qkv + (size_t)b * Tc * 1536 + h * 64 + lane));
    __syncthreads();

    const int t = c * 64 + lane;
    const bool valid = t < Tc;
    float logit = -1e30f;
    if (valid) {
        const bf16* kp = qkv + ((size_t)b * Tc + t) * 1536 + 512 + h * 64;
        float l = 0.f;
        #pragma unroll
        for (int d4 = 0; d4 < 16; ++d4) {
            ushort4 ku = ((const ushort4*)kp)[d4];
            l = fmaf(q0s[d4 * 4 + 0], bf2f(ku.x), l);
            l = fmaf(q0s[d4 * 4 + 1], bf2f(ku.y), l);
            l = fmaf(q0s[d4 * 4 + 2], bf2f(ku.z), l);
            l = fmaf(q0s[d4 * 4 + 3], bf2f(ku.w), l);
        }
        logit = l * 0.125f;
        const bf16* vp = kp + 512;
        #pragma unroll
        for (int d4 = 0; d4 < 16; ++d4) {
            ushort4 vu = ((const ushort4*)vp)[d4];
            vS[lane][d4 * 4 + 0] = bf2f(vu.x);
            vS[lane][d4 * 4 + 1] = bf2f(vu.y);
            vS[lane][d4 * 4 + 2] = bf2f(vu.z);
            vS[lane][d4 * 4 + 3] = bf2f(vu.w);
        }
    } else {
        #pragma unroll
        for (int d = 0; d < 64; ++d) vS[lane][d] = 0.f;
    }

    float m = logit;
    #pragma unroll
    for (int off = 1; off < 64; off <<= 1) m = fmaxf(m, __shfl_xor(m, off));
    float p = valid ? __expf(logit - m) : 0.f;
    float s = p;
    #pragma unroll
    for (int off = 1; off < 64; off <<= 1) s += __shfl_xor(s, off);
    pSm[lane] = p;
    __syncthreads();

    float o = 0.f;
    #pragma unroll
    for (int i = 0; i < 64; ++i) o = fmaf(pSm[i], vS[i][lane], o);

    float* pout = part + ((size_t)(b * Hc + h) * NCh + c) * 66;
    pout[lane] = o;
    if (lane == 0) { pout[64] = m; pout[65] = s; }
}

// ---------------------------------------------------------------------------
// Token-0 reduce (unchanged).
// ---------------------------------------------------------------------------
__global__ __launch_bounds__(64)
void k_tok0_reduce(const float* __restrict__ part, bf16* __restrict__ aout)
{
    const int h = blockIdx.x, b = blockIdx.y;
    const int lane = threadIdx.x;
    const float* base = part + (size_t)(b * Hc + h) * NCh * 66;

    float M = -1e30f;
    for (int c = 0; c < NCh; ++c) M = fmaxf(M, base[c * 66 + 64]);

    float S = 0.f, o = 0.f;
    for (int c = 0; c < NCh; ++c) {
        const float* pp = base + c * 66;
        float w = __expf(pp[64] - M);
        S += pp[65] * w;
        o = fmaf(pp[lane], w, o);
    }
    aout[(size_t)b * Tc * Dc + h * 64 + lane] = __float2bfloat16(o / S);
}

// ---------------------------------------------------------------------------
extern "C" void kernel_launch(void* const* d_in, const int* in_sizes, int n_in,
                              void* d_out, int out_size, void* d_ws, size_t ws_size,
                              hipStream_t stream)
{
    const float* x     = (const float*)d_in[0];
    const float* w_qkv = (const float*)d_in[1];
    const float* w_out = (const float*)d_in[2];
    float* out = (float*)d_out;

    // ws layout (bf16 elems), total 136.6 MB (<= r5's 136.8):
    //   qkv [Mrows*1536] | xa [Mpad2*512] (xb & aout share) | wqT [1536*512]
    //   | woT [512*512].  token-0 partials reuse wqT (dead after QKV GEMM).
    // GEMM A-tail reads (rows < Mpad2) stay inside d_ws; tail C rows are
    // predicated (m < Mrows) and never stored.
    bf16* qkv = (bf16*)d_ws;
    bf16* xa  = qkv + (size_t)Mrows * 1536;
    bf16* wqT = xa  + (size_t)Mpad2 * 512;
    bf16* woT = wqT + (size_t)1536 * 512;
    float* part = (float*)wqT;

    // 1) conversions
    {
        int nblk = (int)(((size_t)Mpad2 * 512 / 8 + 255) / 256);
        k_cvt_x<<<nblk, 256, 0, stream>>>(x, xa);
    }
    k_cvt_wT<<<dim3(48, 16), 256, 0, stream>>>(w_qkv, wqT, 512, 1536);
    k_cvt_wT<<<dim3(16, 16), 256, 0, stream>>>(w_out, woT, 512, 512);

    // 2) qkv = x @ w_qkv  (256^2 8-wave pipelined MFMA)
    k_gemm_8w<bf16, 6><<<129 * 6, 512, 0, stream>>>(xa, wqT, qkv, Mrows);

    // 3) attention: MFMA windows + split-K token-0
    k_attn_win<<<dim3(64, Hc, Bc), 256, 0, stream>>>(qkv, xa);
    k_tok0_part<<<dim3(NCh, Hc, Bc), dim3(64), 0, stream>>>(qkv, part);
    k_tok0_reduce<<<dim3(Hc, Bc), dim3(64), 0, stream>>>(part, xa);

    // 4) out = attn_out @ w_out  (fp32 out)
    k_gemm_8w<float, 2><<<129 * 2, 512, 0, stream>>>(xa, woT, out, Mrows);
}

// Round 7
// 183.720 us; speedup vs baseline: 6.4866x; 1.1713x over previous
//
#include <hip/hip_runtime.h>
#include <hip/hip_bf16.h>
#include <cstdint>
#include <cstddef>

using bf16 = __hip_bfloat16;
using short8 = __attribute__((ext_vector_type(8))) short;
using f32x4  = __attribute__((ext_vector_type(4))) float;

constexpr int Bc = 8;
constexpr int Tc = 4097;
constexpr int Dc = 512;         // model dim
constexpr int Hc = 8;
constexpr int Mrows = Bc * Tc;  // 32776
constexpr int Mpad2 = 33024;    // padded A rows (>= 257*128)
constexpr int NCh = 65;         // token-0 key chunks (64 keys each)

__device__ __forceinline__ float bf2f(unsigned short u) {
    union { unsigned int i; float f; } v;
    v.i = ((unsigned int)u) << 16;
    return v.f;
}

__device__ __forceinline__ unsigned short f2b(float f) {
    union { float f; unsigned int i; } u; u.f = f;
    unsigned int r = u.i + 0x7FFFu + ((u.i >> 16) & 1u);  // RNE
    return (unsigned short)(r >> 16);
}

__device__ __forceinline__ void gload_lds16(const void* g, void* l) {
    __builtin_amdgcn_global_load_lds(
        (const __attribute__((address_space(1))) void*)g,
        (__attribute__((address_space(3))) void*)l, 16, 0, 0);
}

// ---------------------------------------------------------------------------
// Convert x (fp32 [Mrows][512]) -> bf16 [Mpad2][512]; pad rows zeroed.
// ---------------------------------------------------------------------------
__global__ __launch_bounds__(256)
void k_cvt_x(const float* __restrict__ x, bf16* __restrict__ xb)
{
    size_t i8 = ((size_t)blockIdx.x * 256 + threadIdx.x) * 8;
    if (i8 >= (size_t)Mpad2 * 512) return;
    union { short s[8]; short8 v; } o;
    if (i8 < (size_t)Mrows * 512) {
        float4 v0 = *(const float4*)(x + i8);
        float4 v1 = *(const float4*)(x + i8 + 4);
        o.s[0] = (short)f2b(v0.x); o.s[1] = (short)f2b(v0.y);
        o.s[2] = (short)f2b(v0.z); o.s[3] = (short)f2b(v0.w);
        o.s[4] = (short)f2b(v1.x); o.s[5] = (short)f2b(v1.y);
        o.s[6] = (short)f2b(v1.z); o.s[7] = (short)f2b(v1.w);
    } else {
        o.v = short8{0,0,0,0,0,0,0,0};
    }
    *(short8*)((short*)xb + i8) = o.v;
}

// ---------------------------------------------------------------------------
// Convert + transpose weight: w fp32 [K][N] -> wT bf16 [N][K].
// ---------------------------------------------------------------------------
__global__ __launch_bounds__(256)
void k_cvt_wT(const float* __restrict__ w, bf16* __restrict__ wT, int K, int N)
{
    __shared__ float t[32][33];
    int bn = blockIdx.x * 32, bk = blockIdx.y * 32;
    int tx = threadIdx.x & 31, ty = threadIdx.x >> 5;  // 32 x 8
    #pragma unroll
    for (int j = 0; j < 4; ++j)
        t[ty + j * 8][tx] = w[(size_t)(bk + ty + j * 8) * N + bn + tx];
    __syncthreads();
    #pragma unroll
    for (int j = 0; j < 4; ++j)
        wT[(size_t)(bn + ty + j * 8) * K + bk + tx] =
            __float2bfloat16(t[tx][ty + j * 8]);
}

// ---------------------------------------------------------------------------
// 128x128-tile, BK=64, 4-wave (2Mx2N) double-buffered MFMA GEMM with counted
// vmcnt pipeline. 64 KiB LDS => 2 blocks/CU (inter-block TLP hides the
// lockstep vmcnt/barrier stalls that killed the 256^2/1-block variant).
//   C[M][NT*128] = A[.][512] @ Bt[NT*128][512]^T
// Swizzle (conflict-free ds_read_b128, verified 0 conflicts in r6): 16B chunk
// (row, c) holds source chunk ck=(c-row)&7; linear global_load_lds dest;
// fragment k-chunk j read from col (j+row)&7.
// ---------------------------------------------------------------------------
template <typename OutT, int NT>
__global__ __launch_bounds__(256)
void k_gemm_dbuf(const bf16* __restrict__ A, const bf16* __restrict__ Bt,
                 OutT* __restrict__ C, int Mlim)
{
    constexpr int N = NT * 128;
    __shared__ short lds[32768];   // 2 bufs x (A 8192 | B 8192) shorts = 64 KiB

    const int tid = threadIdx.x;
    const int lane = tid & 63, wave = tid >> 6;
    const int lo = lane & 15, g = lane >> 4;
    const int wr = wave >> 1, wc = wave & 1;

    // bijective XCD swizzle (m204), m-tile-major linear id
    const int nwg = 257 * NT;
    const int orig = blockIdx.x;
    const int qq = nwg >> 3, rr = nwg & 7;
    const int xc = orig & 7, o8 = orig >> 3;
    const int swz = (xc < rr ? xc * (qq + 1) : rr * (qq + 1) + (xc - rr) * qq) + o8;
    const int bm = (swz / NT) * 128, bn = (swz % NT) * 128;

    // ---- staging: tile = 128 rows x 8 chunks(16B); thread handles 4 A + 4 B
    const bf16* aSrc[4]; const bf16* bSrc[4];
    int dstOff[4];
    #pragma unroll
    for (int i = 0; i < 4; ++i) {
        int d = i * 256 + tid;
        int row = d >> 3, c = d & 7;
        int ck = (c - row) & 7;                 // rotated source chunk
        aSrc[i] = A  + (size_t)(bm + row) * 512 + ck * 8;
        bSrc[i] = Bt + (size_t)(bn + row) * 512 + ck * 8;
        dstOff[i] = d * 8;                      // linear LDS (shorts)
    }

    auto STAGE = [&](int kt) {
        const int bb = (kt & 1) * 16384;
        #pragma unroll
        for (int i = 0; i < 4; ++i)
            gload_lds16(aSrc[i] + kt * 64, lds + bb + dstOff[i]);
        #pragma unroll
        for (int i = 0; i < 4; ++i)
            gload_lds16(bSrc[i] + kt * 64, lds + bb + 8192 + dstOff[i]);
    };

    // ---- fragment read constants (row stride 64 shorts = 128 B) ----
    const int colk[2] = { (g + (lo & 7)) & 7, (g + 4 + (lo & 7)) & 7 };
    const int arow0 = wr * 64 + lo;
    const int brow0 = wc * 64 + lo;

    f32x4 acc[4][4] = {};

    STAGE(0);
    STAGE(1);
    asm volatile("s_waitcnt vmcnt(8)" ::: "memory");   // K-tile 0 landed
    __builtin_amdgcn_s_barrier();

    for (int t = 0; t < 8; ++t) {
        const short* bufA = lds + (t & 1) * 16384;
        const short* bufB = bufA + 8192;

        #pragma unroll
        for (int ks = 0; ks < 2; ++ks) {
            const int col = colk[ks];
            short8 af[4], bfr[4];
            #pragma unroll
            for (int mi = 0; mi < 4; ++mi)
                af[mi] = *(const short8*)(bufA + (arow0 + mi * 16) * 64 + col * 8);
            #pragma unroll
            for (int ni = 0; ni < 4; ++ni)
                bfr[ni] = *(const short8*)(bufB + (brow0 + ni * 16) * 64 + col * 8);
            __builtin_amdgcn_s_setprio(1);
            #pragma unroll
            for (int mi = 0; mi < 4; ++mi)
                #pragma unroll
                for (int ni = 0; ni < 4; ++ni)
                    acc[mi][ni] = __builtin_amdgcn_mfma_f32_16x16x32_bf16(
                        bfr[ni], af[mi], acc[mi][ni], 0, 0, 0);
            __builtin_amdgcn_s_setprio(0);
        }

        // all waves done reading buf[t&1] before its overwrite by STAGE(t+2)
        asm volatile("s_waitcnt lgkmcnt(0)" ::: "memory");
        __builtin_amdgcn_s_barrier();
        if (t < 6) {
            STAGE(t + 2);                                 // into buf[t&1]
            asm volatile("s_waitcnt vmcnt(8)" ::: "memory");  // K-tile t+1 ready
            __builtin_amdgcn_s_barrier();
        } else if (t == 6) {
            asm volatile("s_waitcnt vmcnt(0)" ::: "memory");  // K-tile 7 ready
            __builtin_amdgcn_s_barrier();
        }
    }

    // ---- epilogue: m = lane&15 dim, n = (lane>>4)*4 + r (vector stores) ----
    #pragma unroll
    for (int mi = 0; mi < 4; ++mi) {
        int m = bm + wr * 64 + mi * 16 + lo;
        if (m < Mlim) {
            #pragma unroll
            for (int ni = 0; ni < 4; ++ni) {
                int n = bn + wc * 64 + ni * 16 + g * 4;
                if constexpr (sizeof(OutT) == 2) {
                    ushort4 o = { f2b(acc[mi][ni][0]), f2b(acc[mi][ni][1]),
                                  f2b(acc[mi][ni][2]), f2b(acc[mi][ni][3]) };
                    *(ushort4*)((bf16*)C + (size_t)m * N + n) = o;
                } else {
                    float4 o = { acc[mi][ni][0], acc[mi][ni][1],
                                 acc[mi][ni][2], acc[mi][ni][3] };
                    *(float4*)((float*)C + (size_t)m * N + n) = o;
                }
            }
        }
    }
}

// ---------------------------------------------------------------------------
// Window attention (tokens 1..4096), MFMA version (unchanged from r3).
// ---------------------------------------------------------------------------
__global__ __launch_bounds__(256)
void k_attn_win(const bf16* __restrict__ qkv, bf16* __restrict__ aout)
{
    __shared__ __attribute__((aligned(16))) unsigned short pS[64 * 64];
    __shared__ __attribute__((aligned(16))) unsigned short vT[64 * 64];

    const int n = blockIdx.x, h = blockIdx.y, b = blockIdx.z;
    const int tid = threadIdx.x;
    const int wave = tid >> 6, lane = tid & 63;
    const int lo = lane & 15, g = lane >> 4;

    const bf16* base = qkv + ((size_t)b * Tc + 1 + (size_t)n * 64) * 1536 + h * 64;
    const bf16* kbase = base + 512;
    const bf16* vbase = base + 1024;

    {
        const int key = tid & 63;
        const int d0 = (tid >> 6) * 16;
        const bf16* vp = vbase + (size_t)key * 1536 + d0;
        ushort4 u[4];
        #pragma unroll
        for (int q = 0; q < 4; ++q) u[q] = *(const ushort4*)(vp + q * 4);
        const unsigned short vals[16] = {
            u[0].x, u[0].y, u[0].z, u[0].w, u[1].x, u[1].y, u[1].z, u[1].w,
            u[2].x, u[2].y, u[2].z, u[2].w, u[3].x, u[3].y, u[3].z, u[3].w };
        #pragma unroll
        for (int j = 0; j < 16; ++j) {
            int d = d0 + j;
            int byteoff = d * 128 + ((key * 2) ^ ((d & 7) << 4));
            *(unsigned short*)((char*)vT + byteoff) = vals[j];
        }
    }

    short8 qf[2];
    {
        const bf16* qp = base + (size_t)(wave * 16 + lo) * 1536 + g * 8;
        qf[0] = *(const short8*)(qp);
        qf[1] = *(const short8*)(qp + 32);
    }

    f32x4 sacc[4] = {};
    #pragma unroll
    for (int ni = 0; ni < 4; ++ni) {
        const bf16* kp = kbase + (size_t)(ni * 16 + lo) * 1536 + g * 8;
        short8 k0 = *(const short8*)(kp);
        short8 k1 = *(const short8*)(kp + 32);
        sacc[ni] = __builtin_amdgcn_mfma_f32_16x16x32_bf16(qf[0], k0, sacc[ni], 0, 0, 0);
        sacc[ni] = __builtin_amdgcn_mfma_f32_16x16x32_bf16(qf[1], k1, sacc[ni], 0, 0, 0);
    }

    __syncthreads();

    float pv[4][4];
    float inv[4];
    #pragma unroll
    for (int r = 0; r < 4; ++r) {
        float m = fmaxf(fmaxf(sacc[0][r], sacc[1][r]),
                        fmaxf(sacc[2][r], sacc[3][r])) * 0.125f;
        m = fmaxf(m, __shfl_xor(m, 1));
        m = fmaxf(m, __shfl_xor(m, 2));
        m = fmaxf(m, __shfl_xor(m, 4));
        m = fmaxf(m, __shfl_xor(m, 8));
        float s = 0.f;
        #pragma unroll
        for (int ni = 0; ni < 4; ++ni) {
            float e = __expf(sacc[ni][r] * 0.125f - m);
            pv[ni][r] = e;
            s += e;
        }
        s += __shfl_xor(s, 1);
        s += __shfl_xor(s, 2);
        s += __shfl_xor(s, 4);
        s += __shfl_xor(s, 8);
        inv[r] = 1.f / s;
    }

    #pragma unroll
    for (int ni = 0; ni < 4; ++ni) {
        #pragma unroll
        for (int r = 0; r < 4; ++r) {
            int qrow = wave * 16 + g * 4 + r;
            int col = ni * 16 + lo;
            int byteoff = qrow * 128 + ((col * 2) ^ ((qrow & 7) << 4));
            *(unsigned short*)((char*)pS + byteoff) = f2b(pv[ni][r]);
        }
    }
    __syncthreads();

    f32x4 oacc[4] = {};
    #pragma unroll
    for (int s = 0; s < 2; ++s) {
        int arow2 = wave * 16 + lo;
        int abyte = arow2 * 128 + (((s * 32 + g * 8) * 2) ^ ((arow2 & 7) << 4));
        short8 pa = *(const short8*)((const char*)pS + abyte);
        #pragma unroll
        for (int nd = 0; nd < 4; ++nd) {
            int d = nd * 16 + lo;
            int bbyte = d * 128 + (((s * 32 + g * 8) * 2) ^ ((d & 7) << 4));
            short8 vb = *(const short8*)((const char*)vT + bbyte);
            oacc[nd] = __builtin_amdgcn_mfma_f32_16x16x32_bf16(pa, vb, oacc[nd], 0, 0, 0);
        }
    }

    #pragma unroll
    for (int nd = 0; nd < 4; ++nd) {
        #pragma unroll
        for (int r = 0; r < 4; ++r) {
            int t = 1 + n * 64 + wave * 16 + g * 4 + r;
            aout[((size_t)b * Tc + t) * Dc + h * 64 + nd * 16 + lo] =
                __float2bfloat16(oacc[nd][r] * inv[r]);
        }
    }
}

// ---------------------------------------------------------------------------
// Token-0 attention, split-K partial (unchanged).
// ---------------------------------------------------------------------------
__global__ __launch_bounds__(64)
void k_tok0_part(const bf16* __restrict__ qkv, float* __restrict__ part)
{
    const int c = blockIdx.x, h = blockIdx.y, b = blockIdx.z;
    const int lane = threadIdx.x;
    __shared__ float q0s[64];
    __shared__ float vS[64][65];
    __shared__ float pSm[64];

    q0s[lane] = bf2f(*(const unsigned short*)
        (qkv + (size_t)b * Tc * 1536 + h * 64 + lane));
    __syncthreads();

    const int t = c * 64 + lane;
    const bool valid = t < Tc;
    float logit = -1e30f;
    if (valid) {
        const bf16* kp = qkv + ((size_t)b * Tc + t) * 1536 + 512 + h * 64;
        float l = 0.f;
        #pragma unroll
        for (int d4 = 0; d4 < 16; ++d4) {
            ushort4 ku = ((const ushort4*)kp)[d4];
            l = fmaf(q0s[d4 * 4 + 0], bf2f(ku.x), l);
            l = fmaf(q0s[d4 * 4 + 1], bf2f(ku.y), l);
            l = fmaf(q0s[d4 * 4 + 2], bf2f(ku.z), l);
            l = fmaf(q0s[d4 * 4 + 3], bf2f(ku.w), l);
        }
        logit = l * 0.125f;
        const bf16* vp = kp + 512;
        #pragma unroll
        for (int d4 = 0; d4 < 16; ++d4) {
            ushort4 vu = ((const ushort4*)vp)[d4];
            vS[lane][d4 * 4 + 0] = bf2f(vu.x);
            vS[lane][d4 * 4 + 1] = bf2f(vu.y);
            vS[lane][d4 * 4 + 2] = bf2f(vu.z);
            vS[lane][d4 * 4 + 3] = bf2f(vu.w);
        }
    } else {
        #pragma unroll
        for (int d = 0; d < 64; ++d) vS[lane][d] = 0.f;
    }

    float m = logit;
    #pragma unroll
    for (int off = 1; off < 64; off <<= 1) m = fmaxf(m, __shfl_xor(m, off));
    float p = valid ? __expf(logit - m) : 0.f;
    float s = p;
    #pragma unroll
    for (int off = 1; off < 64; off <<= 1) s += __shfl_xor(s, off);
    pSm[lane] = p;
    __syncthreads();

    float o = 0.f;
    #pragma unroll
    for (int i = 0; i < 64; ++i) o = fmaf(pSm[i], vS[i][lane], o);

    float* pout = part + ((size_t)(b * Hc + h) * NCh + c) * 66;
    pout[lane] = o;
    if (lane == 0) { pout[64] = m; pout[65] = s; }
}

// ---------------------------------------------------------------------------
// Token-0 reduce (unchanged).
// ---------------------------------------------------------------------------
__global__ __launch_bounds__(64)
void k_tok0_reduce(const float* __restrict__ part, bf16* __restrict__ aout)
{
    const int h = blockIdx.x, b = blockIdx.y;
    const int lane = threadIdx.x;
    const float* base = part + (size_t)(b * Hc + h) * NCh * 66;

    float M = -1e30f;
    for (int c = 0; c < NCh; ++c) M = fmaxf(M, base[c * 66 + 64]);

    float S = 0.f, o = 0.f;
    for (int c = 0; c < NCh; ++c) {
        const float* pp = base + c * 66;
        float w = __expf(pp[64] - M);
        S += pp[65] * w;
        o = fmaf(pp[lane], w, o);
    }
    aout[(size_t)b * Tc * Dc + h * 64 + lane] = __float2bfloat16(o / S);
}

// ---------------------------------------------------------------------------
extern "C" void kernel_launch(void* const* d_in, const int* in_sizes, int n_in,
                              void* d_out, int out_size, void* d_ws, size_t ws_size,
                              hipStream_t stream)
{
    const float* x     = (const float*)d_in[0];
    const float* w_qkv = (const float*)d_in[1];
    const float* w_out = (const float*)d_in[2];
    float* out = (float*)d_out;

    // ws layout (bf16 elems): qkv [Mrows*1536] | xa [Mpad2*512] (xb & aout
    // share; rows >= Mrows stay zero from cvt_x pad) | wqT [1536*512] |
    // woT [512*512]. token-0 partials reuse wqT (dead after QKV GEMM).
    bf16* qkv = (bf16*)d_ws;
    bf16* xa  = qkv + (size_t)Mrows * 1536;
    bf16* wqT = xa  + (size_t)Mpad2 * 512;
    bf16* woT = wqT + (size_t)1536 * 512;
    float* part = (float*)wqT;

    // 1) conversions
    {
        int nblk = (int)(((size_t)Mpad2 * 512 / 8 + 255) / 256);
        k_cvt_x<<<nblk, 256, 0, stream>>>(x, xa);
    }
    k_cvt_wT<<<dim3(48, 16), 256, 0, stream>>>(w_qkv, wqT, 512, 1536);
    k_cvt_wT<<<dim3(16, 16), 256, 0, stream>>>(w_out, woT, 512, 512);

    // 2) qkv = x @ w_qkv  (128^2 4-wave dbuf MFMA, 2 blocks/CU)
    k_gemm_dbuf<bf16, 12><<<257 * 12, 256, 0, stream>>>(xa, wqT, qkv, Mrows);

    // 3) attention: MFMA windows + split-K token-0
    k_attn_win<<<dim3(64, Hc, Bc), 256, 0, stream>>>(qkv, xa);
    k_tok0_part<<<dim3(NCh, Hc, Bc), dim3(64), 0, stream>>>(qkv, part);
    k_tok0_reduce<<<dim3(Hc, Bc), dim3(64), 0, stream>>>(part, xa);

    // 4) out = attn_out @ w_out  (fp32 out)
    k_gemm_dbuf<float, 4><<<257 * 4, 256, 0, stream>>>(xa, woT, out, Mrows);
}